// Round 3
// baseline (965.465 us; speedup 1.0000x reference)
//
#include <hip/hip_runtime.h>
#include <hip/hip_bf16.h>

#define Bc 16
#define Hc 56
#define Wcc 56
#define Cc 192
#define NHc 6
#define Lc 3136
#define DHc 32
#define HIDc 768
#define NHEAD 96          // B*NH
#define Sc 32             // chunk length
#define NCHUNK 98         // chunks per head (98*32 = 3136)
#define NPAIR (NHEAD*NCHUNK)
#define ROWS (Bc*Lc)      // 50176
#define GROUPROWS (ROWS/4)
#define ETAc (1.0f/32.0f)

typedef unsigned short u16;
typedef unsigned int u32;
typedef __attribute__((ext_vector_type(8))) short bf16x8;
typedef __attribute__((ext_vector_type(4))) float f32x4;
typedef __attribute__((ext_vector_type(16))) float f32x16;

__device__ __forceinline__ float b2f(u16 v){ u32 u = ((u32)v)<<16; float f; __builtin_memcpy(&f,&u,4); return f; }
__device__ __forceinline__ u16 f2b(float f){ u32 u; __builtin_memcpy(&u,&f,4); u32 r = u + 0x7FFFu + ((u>>16)&1u); return (u16)(r>>16); }
__device__ __forceinline__ f32x16 zero16(){ f32x16 z = {0,0,0,0,0,0,0,0,0,0,0,0,0,0,0,0}; return z; }

// ---------------- weight cast ----------------
__global__ __launch_bounds__(256) void cast_bf16_kernel(const float* __restrict__ src, u16* __restrict__ dst, int n){
  int i = blockIdx.x*256 + threadIdx.x;
  if (i < n) dst[i] = f2b(src[i]);
}

// ---------------- rope tables ----------------
__global__ __launch_bounds__(256) void rope_tab_kernel(float* __restrict__ ct, float* __restrict__ st){
  int i = blockIdx.x*256 + threadIdx.x;   // < Lc*96
  int l = i/96, p = i - l*96;
  int h = l/Wcc, w = l - h*Wcc;
  int kk = (p<48)? p : p-48;
  float th = powf(10000.f, -(float)kk/48.f);
  float ang = (float)((p<48)? h : w) * th;
  ct[i] = cosf(ang);
  st[i] = sinf(ang);
}

// ---------------- CPE depthwise conv (C=192), out bf16 ----------------
__global__ __launch_bounds__(192) void cpe_kernel(const float* __restrict__ x, const float* __restrict__ wt,
                                                  const float* __restrict__ bs, u16* __restrict__ x1){
  int c = threadIdx.x;
  int row = blockIdx.x;                 // b*Lc + l
  int l = row % Lc; int h = l/Wcc, w = l - h*Wcc;
  const float* xp = x + (size_t)row*Cc;
  float acc = bs[c];
  #pragma unroll
  for (int kh=0;kh<3;kh++){
    int hh = h+kh-1; if (hh<0 || hh>=Hc) continue;
    #pragma unroll
    for (int kw=0;kw<3;kw++){
      int ww = w+kw-1; if (ww<0 || ww>=Wcc) continue;
      acc += xp[((kh-1)*Wcc + (kw-1))*Cc + c] * wt[c*9 + kh*3 + kw];
    }
  }
  x1[(size_t)row*Cc + c] = f2b(xp[c] + acc);
}

// ---------------- LayerNorm -> bf16.  INF32=0: bf16 input, 1: fp32 input ----------------
template<int INF32>
__global__ __launch_bounds__(256) void ln_kernel(const u16* __restrict__ xb, const float* __restrict__ xf,
                                                 const float* __restrict__ g, const float* __restrict__ b,
                                                 u16* __restrict__ out){
  int row = blockIdx.x*4 + (threadIdx.x>>6);
  int lane = threadIdx.x & 63;
  float v0, v1, v2;
  if (INF32){
    const float* xr = xf + (size_t)row*Cc;
    v0 = xr[lane]; v1 = xr[lane+64]; v2 = xr[lane+128];
  } else {
    const u16* xr = xb + (size_t)row*Cc;
    v0 = b2f(xr[lane]); v1 = b2f(xr[lane+64]); v2 = b2f(xr[lane+128]);
  }
  float s = v0+v1+v2;
  float q = v0*v0 + v1*v1 + v2*v2;
  #pragma unroll
  for (int off=32; off; off>>=1){ s += __shfl_xor(s, off); q += __shfl_xor(q, off); }
  float mu = s*(1.f/Cc);
  float var = q*(1.f/Cc) - mu*mu;
  float rs = rsqrtf(var + 1e-5f);
  u16* orow = out + (size_t)row*Cc;
  orow[lane]     = f2b((v0-mu)*rs*g[lane]     + b[lane]);
  orow[lane+64]  = f2b((v1-mu)*rs*g[lane+64]  + b[lane+64]);
  orow[lane+128] = f2b((v2-mu)*rs*g[lane+128] + b[lane+128]);
}

// ---------------- generic GEMM: out = epilogue(A[M,K](bf16) @ W[N,K]^T(bf16) + bias) ----------------
// MODE 0: qkv  (col<384 -> qk bf16, col>=384 -> vdst bf16 per-head layout)
// MODE 1: fp32 out (width Cc) = val + b2f(residb)        [proj]
// MODE 2: bf16 out (width HIDc) = gelu(val)              [fc1]
// MODE 3: fp32 out (width Cc) = val + residf             [fc2]
template<int MODE>
__global__ __launch_bounds__(256) void gemm_kernel(
    const u16* __restrict__ A, const u16* __restrict__ Wt,
    const float* __restrict__ bias, int K,
    float* __restrict__ outf, u16* __restrict__ outb,
    u16* __restrict__ vdst, const u16* __restrict__ residb, const float* __restrict__ residf)
{
  int wid = threadIdx.x>>6, lane = threadIdx.x&63;
  int m0 = blockIdx.x*64 + (wid>>1)*32;
  int n0 = blockIdx.y*192 + (wid&1)*96;
  int ar = lane&15, kg = (lane>>4)*8;
  f32x4 acc[2][6];
  #pragma unroll
  for (int r=0;r<2;r++)
    #pragma unroll
    for (int c=0;c<6;c++){ f32x4 z = {0.f,0.f,0.f,0.f}; acc[r][c] = z; }
  for (int k0=0;k0<K;k0+=32){
    bf16x8 af[2], bfr[6];
    #pragma unroll
    for (int r=0;r<2;r++) af[r] = *(const bf16x8*)(A + (size_t)(m0 + r*16 + ar)*K + k0 + kg);
    #pragma unroll
    for (int c=0;c<6;c++) bfr[c] = *(const bf16x8*)(Wt + (size_t)(n0 + c*16 + ar)*K + k0 + kg);
    #pragma unroll
    for (int r=0;r<2;r++)
      #pragma unroll
      for (int c=0;c<6;c++)
        acc[r][c] = __builtin_amdgcn_mfma_f32_16x16x32_bf16(af[r], bfr[c], acc[r][c], 0,0,0);
  }
  int rb = (lane>>4)*4;
  #pragma unroll
  for (int r=0;r<2;r++){
    #pragma unroll
    for (int c=0;c<6;c++){
      int col = n0 + c*16 + ar;
      float bv = bias[col];
      #pragma unroll
      for (int j=0;j<4;j++){
        int row = m0 + r*16 + rb + j;
        float v = acc[r][c][j] + bv;
        if (MODE==0){
          if (col < 384) outb[(size_t)row*384 + col] = f2b(v);
          else {
            int bb = row/Lc; int l = row - bb*Lc;
            int nh = (col-384)>>5; int d = col&31;
            vdst[(((size_t)(bb*NHc+nh))*Lc + l)*DHc + d] = f2b(v);
          }
        } else if (MODE==1){
          outf[(size_t)row*Cc + col] = v + b2f(residb[(size_t)row*Cc + col]);
        } else if (MODE==2){
          float gv = 0.5f*v*(1.f + erff(v*0.70710678118654752f));
          outb[(size_t)row*HIDc + col] = f2b(gv);
        } else {
          outf[(size_t)row*Cc + col] = v + residf[(size_t)row*Cc + col];
        }
      }
    }
  }
}

// ---------------- rope + head reorder ----------------
__global__ __launch_bounds__(256) void rope_kernel(const u16* __restrict__ qk, const float* __restrict__ ct,
                                                   const float* __restrict__ st, u16* __restrict__ q_s, u16* __restrict__ k_s){
  int gid = blockIdx.x*256 + threadIdx.x;   // < ROWS*192 (one pair each)
  int pp = gid % 192; int row = gid / 192;
  int bb = row / Lc; int l = row - bb*Lc;
  bool isq = pp < 96; int p = isq ? pp : pp-96;
  int cbase = (isq ? 0 : 192) + 2*p;
  const u16* qr = qk + (size_t)row*384 + cbase;
  float re = b2f(qr[0]), im = b2f(qr[1]);
  float cs = ct[l*96+p], sn = st[l*96+p];
  float r2 = cs*re - sn*im;
  float i2 = sn*re + cs*im;
  if (isq){ r2 *= 0.1767766952966369f; i2 *= 0.1767766952966369f; }
  int nh = p>>4, d = (2*p)&31;
  u16* dst = (isq ? q_s : k_s) + (((size_t)(bb*NHc+nh))*Lc + l)*DHc + d;
  dst[0] = f2b(r2);
  dst[1] = f2b(i2);
}

// ---------------- phase A: per (head,chunk) triangular solve -> U, R ----------------
__global__ __launch_bounds__(64) void ttta_kernel(const u16* __restrict__ k_s, const u16* __restrict__ v_s,
                                                  u16* __restrict__ u_s, u16* __restrict__ r_s){
  __shared__ float Gl[Sc*Sc];
  int pair = blockIdx.x;
  int head = pair / NCHUNK;
  int l0 = (pair - head*NCHUNK) * Sc;
  int lane = threadIdx.x;
  const u16* kb = k_s + ((size_t)head*Lc + l0)*DHc;
  int rr = lane&31, ks = (lane>>5)*8;
  bf16x8 a0 = *(const bf16x8*)(kb + rr*32 + ks);
  bf16x8 a1 = *(const bf16x8*)(kb + rr*32 + 16 + ks);
  f32x16 g = zero16();
  g = __builtin_amdgcn_mfma_f32_32x32x16_bf16(a0, a0, g, 0,0,0);
  g = __builtin_amdgcn_mfma_f32_32x32x16_bf16(a1, a1, g, 0,0,0);
  #pragma unroll
  for (int reg=0;reg<16;reg++){
    int i = (reg&3) + 8*(reg>>2) + 4*(lane>>5);
    Gl[i*32 + rr] = ETAc * g[reg];
  }
  __syncthreads();
  float X[32];
  if (lane < 32){
    #pragma unroll
    for (int i=0;i<32;i++) X[i] = ETAc * b2f(v_s[((size_t)head*Lc + l0 + i)*DHc + lane]);
  } else {
    int m = lane-32;
    #pragma unroll
    for (int i=0;i<32;i++) X[i] = ETAc * b2f(kb[i*32 + m]);
  }
  #pragma unroll
  for (int i=1;i<32;i++){
    float a = X[i];
    #pragma unroll
    for (int j=0;j<i;j++) a -= Gl[i*32+j]*X[j];
    X[i] = a;
  }
  u16* dst = (lane<32 ? u_s : r_s) + (size_t)pair*1024 + (lane&31);
  #pragma unroll
  for (int i=0;i<32;i++) dst[i*32] = f2b(X[i]);
}

// ---------------- phase B: sequential state propagation per head ----------------
// NOTE: t0_s aliases u_s, wr_s aliases r_s (in-place per chunk: chunk c is consumed
// into registers (prefetch at c-1) before its slot is overwritten).
__global__ __launch_bounds__(512) void tttb_kernel(const u16* __restrict__ u_s, const u16* __restrict__ r_s,
                                                   const u16* __restrict__ k_s, const float* __restrict__ W0,
                                                   u16* __restrict__ t0_s, u16* __restrict__ wr_s){
  __shared__ float T[1024], Uf[1024], Rf[1024], Kf[1024], Wr[1024];
  int head = blockIdx.x;
  int nh = head % NHc;
  int t = threadIdx.x;
  #pragma unroll
  for (int k=0;k<2;k++){
    int fl = t + 512*k;
    T[fl] = W0[nh*1024 + (fl&31)*32 + (fl>>5)];   // T[a][b] = W0[b][a]  (T = W^T)
  }
  const u32* U32 = (const u32*)u_s;
  const u32* R32 = (const u32*)r_s;
  const u32* K32 = (const u32*)k_s;
  size_t ubase = (size_t)head*NCHUNK*512;
  size_t kbase = (size_t)head*(Lc*DHc/2);
  u32 pu = U32[ubase + t];
  u32 pr = R32[ubase + t];
  u32 pk = K32[kbase + t];
  int r = t&31, ig = t>>5;   // ig in [0,16)
  for (int c=0;c<NCHUNK;c++){
    Uf[2*t] = b2f((u16)pu); Uf[2*t+1] = b2f((u16)(pu>>16));
    Rf[2*t] = b2f((u16)pr); Rf[2*t+1] = b2f((u16)(pr>>16));
    Kf[2*t] = b2f((u16)pk); Kf[2*t+1] = b2f((u16)(pk>>16));
    __syncthreads();
    if (c+1 < NCHUNK){
      size_t uo = ubase + (size_t)(c+1)*512;
      size_t ko = kbase + (size_t)(c+1)*512;
      pu = U32[uo + t]; pr = R32[uo + t]; pk = K32[ko + t];
    }
    size_t pof = (size_t)(head*NCHUNK + c)*1024;
    #pragma unroll
    for (int k=0;k<2;k++){ int fl = t+512*k; t0_s[pof+fl] = f2b(T[fl]); }
    float tcol[32];
    #pragma unroll
    for (int m=0;m<32;m++) tcol[m] = T[m*32+r];
    float w2[2];
    #pragma unroll
    for (int k=0;k<2;k++){
      int i = ig + 16*k;
      float a = Uf[i*32+r];
      #pragma unroll
      for (int m=0;m<32;m++) a -= Rf[i*32+m]*tcol[m];
      w2[k] = a;
    }
    #pragma unroll
    for (int k=0;k<2;k++){ int i = ig+16*k; Wr[i*32+r] = w2[k]; wr_s[pof + i*32+r] = f2b(w2[k]); }
    __syncthreads();
    float wcol[32];
    #pragma unroll
    for (int m=0;m<32;m++) wcol[m] = Wr[m*32+r];
    #pragma unroll
    for (int k=0;k<2;k++){
      int cc = ig + 16*k;
      float a = T[cc*32+r];
      #pragma unroll
      for (int i=0;i<32;i++) a += Kf[i*32+cc]*wcol[i];
      T[cc*32+r] = a;
    }
    __syncthreads();
  }
}

// ---------------- phase C: outputs O = Q*W0^T + tril(Q K^T)*W_rows ----------------
__global__ __launch_bounds__(64) void tttc_kernel(const u16* __restrict__ q_s, const u16* __restrict__ k_s,
                                                  const u16* __restrict__ t0_s, const u16* __restrict__ wr_s,
                                                  u16* __restrict__ o_bf){
  __shared__ __align__(16) u16 Pl[32*40];
  int pair = blockIdx.x;
  int head = pair / NCHUNK;
  int ch = pair - head*NCHUNK;
  int l0 = ch*Sc;
  int lane = threadIdx.x; int rr = lane&31, ks = (lane>>5)*8;
  const u16* qb = q_s + ((size_t)head*Lc + l0)*DHc;
  const u16* kb = k_s + ((size_t)head*Lc + l0)*DHc;
  bf16x8 q0 = *(const bf16x8*)(qb + rr*32 + ks);
  bf16x8 q1 = *(const bf16x8*)(qb + rr*32 + 16 + ks);
  bf16x8 k0 = *(const bf16x8*)(kb + rr*32 + ks);
  bf16x8 k1 = *(const bf16x8*)(kb + rr*32 + 16 + ks);
  f32x16 p = zero16();
  p = __builtin_amdgcn_mfma_f32_32x32x16_bf16(q0, k0, p, 0,0,0);
  p = __builtin_amdgcn_mfma_f32_32x32x16_bf16(q1, k1, p, 0,0,0);
  #pragma unroll
  for (int reg=0;reg<16;reg++){
    int i = (reg&3)+8*(reg>>2)+4*(lane>>5);
    Pl[i*40+rr] = (rr<=i) ? f2b(p[reg]) : (u16)0;
  }
  __syncthreads();
  const u16* t0b = t0_s + (size_t)pair*1024;
  const u16* wrb = wr_s + (size_t)pair*1024;
  union { bf16x8 v; short s[8]; } tb0, tb1, wb0, wb1;
  #pragma unroll
  for (int mm=0;mm<8;mm++){
    tb0.s[mm] = (short)t0b[(ks+mm)*32 + rr];
    tb1.s[mm] = (short)t0b[(16+ks+mm)*32 + rr];
    wb0.s[mm] = (short)wrb[(ks+mm)*32 + rr];
    wb1.s[mm] = (short)wrb[(16+ks+mm)*32 + rr];
  }
  f32x16 o = zero16();
  o = __builtin_amdgcn_mfma_f32_32x32x16_bf16(q0, tb0.v, o, 0,0,0);
  o = __builtin_amdgcn_mfma_f32_32x32x16_bf16(q1, tb1.v, o, 0,0,0);
  bf16x8 pa0 = *(const bf16x8*)(Pl + rr*40 + ks);
  bf16x8 pa1 = *(const bf16x8*)(Pl + rr*40 + 16 + ks);
  o = __builtin_amdgcn_mfma_f32_32x32x16_bf16(pa0, wb0.v, o, 0,0,0);
  o = __builtin_amdgcn_mfma_f32_32x32x16_bf16(pa1, wb1.v, o, 0,0,0);
  int bb = head/NHc, nh = head - bb*NHc;
  #pragma unroll
  for (int reg=0;reg<16;reg++){
    int i = (reg&3)+8*(reg>>2)+4*(lane>>5);
    o_bf[((size_t)(bb*Lc + l0 + i))*Cc + nh*32 + rr] = f2b(o[reg]);
  }
}

// ---------------- MLP depthwise conv (HID=768) + gelu, row-group version ----------------
__global__ __launch_bounds__(256) void dwc_kernel(const u16* __restrict__ h1, const float* __restrict__ wt,
                                                  const float* __restrict__ bs, u16* __restrict__ h2, int row0){
  int gid = blockIdx.x*256 + threadIdx.x;   // < GROUPROWS*HIDc
  int ch = gid % HIDc; int lrow = gid / HIDc;
  int row = row0 + lrow;
  int l = row % Lc; int h = l/Wcc, w = l - h*Wcc;
  const u16* hp = h1 + (size_t)lrow*HIDc + ch;
  float acc = bs[ch];
  #pragma unroll
  for (int kh=0;kh<3;kh++){
    int hh = h+kh-1; if (hh<0 || hh>=Hc) continue;
    #pragma unroll
    for (int kw=0;kw<3;kw++){
      int ww = w+kw-1; if (ww<0 || ww>=Wcc) continue;
      acc += b2f(hp[((kh-1)*Wcc + (kw-1))*HIDc]) * wt[ch*9 + kh*3 + kw];
    }
  }
  float v = b2f(hp[0]) + acc;
  h2[(size_t)lrow*HIDc + ch] = f2b(0.5f*v*(1.f + erff(v*0.70710678118654752f)));
}

// ---------------- launch ----------------
extern "C" void kernel_launch(void* const* d_in, const int* in_sizes, int n_in,
                              void* d_out, int out_size, void* d_ws, size_t ws_size,
                              hipStream_t stream){
  const float* x     = (const float*)d_in[0];
  const float* cpe_w = (const float*)d_in[1];
  const float* cpe_b = (const float*)d_in[2];
  const float* n1_g  = (const float*)d_in[3];
  const float* n1_b  = (const float*)d_in[4];
  const float* qkv_w = (const float*)d_in[5];
  const float* qkv_b = (const float*)d_in[6];
  const float* W0    = (const float*)d_in[7];
  const float* proj_w= (const float*)d_in[8];
  const float* proj_b= (const float*)d_in[9];
  const float* n2_g  = (const float*)d_in[10];
  const float* n2_b  = (const float*)d_in[11];
  const float* fc1_w = (const float*)d_in[12];
  const float* fc1_b = (const float*)d_in[13];
  const float* dwc_w = (const float*)d_in[14];
  const float* dwc_b = (const float*)d_in[15];
  const float* fc2_w = (const float*)d_in[16];
  const float* fc2_b = (const float*)d_in[17];

  char* ws = (char*)d_ws;
  size_t off = 0;
  auto alloc = [&](size_t bytes)->char*{
    char* p = ws + off;
    off += (bytes + 255) & ~(size_t)255;
    return p;
  };
  // arena: ~80.4 MB total
  u16* wbqkv = (u16*)alloc((size_t)576*192*2);
  u16* wbproj= (u16*)alloc((size_t)192*192*2);
  u16* wbfc1 = (u16*)alloc((size_t)768*192*2);
  u16* wbfc2 = (u16*)alloc((size_t)192*768*2);
  float* ctab = (float*)alloc((size_t)Lc*96*4);
  float* stab = (float*)alloc((size_t)Lc*96*4);
  u16* regA = (u16*)alloc((size_t)ROWS*Cc*2);   // x1(bf16) -> h1 group
  u16* regB = (u16*)alloc((size_t)ROWS*Cc*2);   // xn -> qs -> xn2
  u16* regD = (u16*)alloc((size_t)NHEAD*Lc*DHc*2); // vs -> obf -> h2 group
  u16* regE = (u16*)alloc((size_t)NHEAD*Lc*DHc*2); // ksb
  // d_out (38,535,168 B) as scratch region O: qk -> us/rs -> t0s/wrs(in-place) -> x2 -> final
  u16* qk = (u16*)d_out;
  u16* us = (u16*)d_out;
  u16* rs = us + (size_t)NPAIR*1024;
  float* x2 = (float*)d_out;

  u16* x1 = regA;
  u16* xn = regB;
  u16* qs = regB;
  u16* xn2 = regB;
  u16* vs = regD;
  u16* obf = regD;
  u16* ksb = regE;

  cast_bf16_kernel<<<(576*192+255)/256,256,0,stream>>>(qkv_w, wbqkv, 576*192);
  cast_bf16_kernel<<<(192*192+255)/256,256,0,stream>>>(proj_w, wbproj, 192*192);
  cast_bf16_kernel<<<(768*192+255)/256,256,0,stream>>>(fc1_w, wbfc1, 768*192);
  cast_bf16_kernel<<<(192*768+255)/256,256,0,stream>>>(fc2_w, wbfc2, 192*768);
  rope_tab_kernel<<<(Lc*96)/256,256,0,stream>>>(ctab, stab);

  cpe_kernel<<<ROWS,192,0,stream>>>(x, cpe_w, cpe_b, x1);
  ln_kernel<0><<<ROWS/4,256,0,stream>>>(x1, nullptr, n1_g, n1_b, xn);
  { dim3 g(ROWS/64, 3); gemm_kernel<0><<<g,256,0,stream>>>(xn, wbqkv, qkv_b, 192, nullptr, qk, vs, nullptr, nullptr); }
  rope_kernel<<<(ROWS*192)/256,256,0,stream>>>(qk, ctab, stab, qs, ksb);
  ttta_kernel<<<NPAIR,64,0,stream>>>(ksb, vs, us, rs);
  tttb_kernel<<<NHEAD,512,0,stream>>>(us, rs, ksb, W0, us /*t0s in-place*/, rs /*wrs in-place*/);
  tttc_kernel<<<NPAIR,64,0,stream>>>(qs, ksb, us, rs, obf);
  { dim3 g(ROWS/64, 1); gemm_kernel<1><<<g,256,0,stream>>>(obf, wbproj, proj_b, 192, x2, nullptr, nullptr, x1, nullptr); }
  ln_kernel<1><<<ROWS/4,256,0,stream>>>(nullptr, x2, n2_g, n2_b, xn2);
  for (int g4=0; g4<4; g4++){
    const u16* a_in = xn2 + (size_t)g4*GROUPROWS*Cc;
    u16* h1 = regA;
    u16* h2 = regD;
    float* xo = x2 + (size_t)g4*GROUPROWS*Cc;
    { dim3 g(GROUPROWS/64, 4); gemm_kernel<2><<<g,256,0,stream>>>(a_in, wbfc1, fc1_b, 192, nullptr, h1, nullptr, nullptr, nullptr); }
    dwc_kernel<<<(GROUPROWS*HIDc)/256,256,0,stream>>>(h1, dwc_w, dwc_b, h2, g4*GROUPROWS);
    { dim3 g(GROUPROWS/64, 1); gemm_kernel<3><<<g,256,0,stream>>>(h2, wbfc2, fc2_b, 768, xo, nullptr, nullptr, nullptr, xo); }
  }
}

// Round 4
// 641.299 us; speedup vs baseline: 1.5055x; 1.5055x over previous
//
#include <hip/hip_runtime.h>
#include <hip/hip_bf16.h>

#define Bc 16
#define Hc 56
#define Wcc 56
#define Cc 192
#define NHc 6
#define Lc 3136
#define DHc 32
#define HIDc 768
#define NHEAD 96          // B*NH
#define Sc 32             // chunk length
#define NCHUNK 98         // chunks per head (98*32 = 3136)
#define NPAIR (NHEAD*NCHUNK)
#define ROWS (Bc*Lc)      // 50176
#define GROUPROWS (ROWS/4)
#define ETAc (1.0f/32.0f)

typedef unsigned short u16;
typedef unsigned int u32;
typedef __attribute__((ext_vector_type(8))) short bf16x8;
typedef __attribute__((ext_vector_type(4))) float f32x4;
typedef __attribute__((ext_vector_type(16))) float f32x16;

__device__ __forceinline__ float b2f(u16 v){ u32 u = ((u32)v)<<16; float f; __builtin_memcpy(&f,&u,4); return f; }
__device__ __forceinline__ u16 f2b(float f){ u32 u; __builtin_memcpy(&u,&f,4); u32 r = u + 0x7FFFu + ((u>>16)&1u); return (u16)(r>>16); }
__device__ __forceinline__ f32x16 zero16(){ f32x16 z = {0,0,0,0,0,0,0,0,0,0,0,0,0,0,0,0}; return z; }

// Build b-operand (and a-operand; same layout) bf16 fragments from an f32 accumulator.
// Input: acc layout lane rr holds M[i][rr], i = (r&3)+8*(r>>2)+4*hi  (32x32 mfma C/D layout)
// Output: b1 lane slots s = M[ks+s][rr], b2 slots s = M[16+ks+s][rr], ks=hi*8.
__device__ __forceinline__ void make_bfrags(const f32x16& t, int hi, bf16x8& b1, bf16x8& b2){
  u32 P[8], S[8];
  #pragma unroll
  for (int q=0;q<4;q++){
    #pragma unroll
    for (int j=0;j<2;j++){
      u32 r; float lo = t[4*q+2*j], hv = t[4*q+2*j+1];
      asm("v_cvt_pk_bf16_f32 %0, %1, %2" : "=v"(r) : "v"(lo), "v"(hv));
      P[2*q+j] = r;
    }
  }
  #pragma unroll
  for (int i=0;i<8;i++) S[i] = (u32)__shfl_xor((int)P[i], 32);
  union { u32 u[4]; bf16x8 v; } f1, f2;
  if (hi==0){ f1.u[0]=P[0]; f1.u[1]=P[1]; f1.u[2]=S[0]; f1.u[3]=S[1];
              f2.u[0]=P[4]; f2.u[1]=P[5]; f2.u[2]=S[4]; f2.u[3]=S[5]; }
  else      { f1.u[0]=S[2]; f1.u[1]=S[3]; f1.u[2]=P[2]; f1.u[3]=P[3];
              f2.u[0]=S[6]; f2.u[1]=S[7]; f2.u[2]=P[6]; f2.u[3]=P[7]; }
  b1 = f1.v; b2 = f2.v;
}

// ---------------- weight cast ----------------
__global__ __launch_bounds__(256) void cast_bf16_kernel(const float* __restrict__ src, u16* __restrict__ dst, int n){
  int i = blockIdx.x*256 + threadIdx.x;
  if (i < n) dst[i] = f2b(src[i]);
}

// ---------------- dwc weight transpose: (768,9) -> (9,768) ----------------
__global__ __launch_bounds__(256) void dwt_kernel(const float* __restrict__ w, float* __restrict__ wt){
  int i = blockIdx.x*256 + threadIdx.x;   // < 768*9
  int ch = i/9, t = i - ch*9;
  wt[t*HIDc + ch] = w[i];
}

// ---------------- rope tables ----------------
__global__ __launch_bounds__(256) void rope_tab_kernel(float* __restrict__ ct, float* __restrict__ st){
  int i = blockIdx.x*256 + threadIdx.x;   // < Lc*96
  int l = i/96, p = i - l*96;
  int h = l/Wcc, w = l - h*Wcc;
  int kk = (p<48)? p : p-48;
  float th = powf(10000.f, -(float)kk/48.f);
  float ang = (float)((p<48)? h : w) * th;
  ct[i] = cosf(ang);
  st[i] = sinf(ang);
}

// ---------------- CPE depthwise conv (C=192), out bf16 ----------------
__global__ __launch_bounds__(192) void cpe_kernel(const float* __restrict__ x, const float* __restrict__ wt,
                                                  const float* __restrict__ bs, u16* __restrict__ x1){
  int c = threadIdx.x;
  int row = blockIdx.x;                 // b*Lc + l
  int l = row % Lc; int h = l/Wcc, w = l - h*Wcc;
  const float* xp = x + (size_t)row*Cc;
  float acc = bs[c];
  #pragma unroll
  for (int kh=0;kh<3;kh++){
    int hh = h+kh-1; if (hh<0 || hh>=Hc) continue;
    #pragma unroll
    for (int kw=0;kw<3;kw++){
      int ww = w+kw-1; if (ww<0 || ww>=Wcc) continue;
      acc += xp[((kh-1)*Wcc + (kw-1))*Cc + c] * wt[c*9 + kh*3 + kw];
    }
  }
  x1[(size_t)row*Cc + c] = f2b(xp[c] + acc);
}

// ---------------- LayerNorm -> bf16.  INF32=0: bf16 input, 1: fp32 input ----------------
template<int INF32>
__global__ __launch_bounds__(256) void ln_kernel(const u16* __restrict__ xb, const float* __restrict__ xf,
                                                 const float* __restrict__ g, const float* __restrict__ b,
                                                 u16* __restrict__ out){
  int row = blockIdx.x*4 + (threadIdx.x>>6);
  int lane = threadIdx.x & 63;
  float v0, v1, v2;
  if (INF32){
    const float* xr = xf + (size_t)row*Cc;
    v0 = xr[lane]; v1 = xr[lane+64]; v2 = xr[lane+128];
  } else {
    const u16* xr = xb + (size_t)row*Cc;
    v0 = b2f(xr[lane]); v1 = b2f(xr[lane+64]); v2 = b2f(xr[lane+128]);
  }
  float s = v0+v1+v2;
  float q = v0*v0 + v1*v1 + v2*v2;
  #pragma unroll
  for (int off=32; off; off>>=1){ s += __shfl_xor(s, off); q += __shfl_xor(q, off); }
  float mu = s*(1.f/Cc);
  float var = q*(1.f/Cc) - mu*mu;
  float rs = rsqrtf(var + 1e-5f);
  u16* orow = out + (size_t)row*Cc;
  orow[lane]     = f2b((v0-mu)*rs*g[lane]     + b[lane]);
  orow[lane+64]  = f2b((v1-mu)*rs*g[lane+64]  + b[lane+64]);
  orow[lane+128] = f2b((v2-mu)*rs*g[lane+128] + b[lane+128]);
}

// ---------------- generic GEMM: out = epilogue(A[M,K](bf16) @ W[N,K]^T(bf16) + bias) ----------------
template<int MODE>
__global__ __launch_bounds__(256) void gemm_kernel(
    const u16* __restrict__ A, const u16* __restrict__ Wt,
    const float* __restrict__ bias, int K,
    float* __restrict__ outf, u16* __restrict__ outb,
    u16* __restrict__ vdst, const u16* __restrict__ residb, const float* __restrict__ residf)
{
  int wid = threadIdx.x>>6, lane = threadIdx.x&63;
  int m0 = blockIdx.x*64 + (wid>>1)*32;
  int n0 = blockIdx.y*192 + (wid&1)*96;
  int ar = lane&15, kg = (lane>>4)*8;
  f32x4 acc[2][6];
  #pragma unroll
  for (int r=0;r<2;r++)
    #pragma unroll
    for (int c=0;c<6;c++){ f32x4 z = {0.f,0.f,0.f,0.f}; acc[r][c] = z; }
  for (int k0=0;k0<K;k0+=32){
    bf16x8 af[2], bfr[6];
    #pragma unroll
    for (int r=0;r<2;r++) af[r] = *(const bf16x8*)(A + (size_t)(m0 + r*16 + ar)*K + k0 + kg);
    #pragma unroll
    for (int c=0;c<6;c++) bfr[c] = *(const bf16x8*)(Wt + (size_t)(n0 + c*16 + ar)*K + k0 + kg);
    #pragma unroll
    for (int r=0;r<2;r++)
      #pragma unroll
      for (int c=0;c<6;c++)
        acc[r][c] = __builtin_amdgcn_mfma_f32_16x16x32_bf16(af[r], bfr[c], acc[r][c], 0,0,0);
  }
  int rb = (lane>>4)*4;
  #pragma unroll
  for (int r=0;r<2;r++){
    #pragma unroll
    for (int c=0;c<6;c++){
      int col = n0 + c*16 + ar;
      float bv = bias[col];
      #pragma unroll
      for (int j=0;j<4;j++){
        int row = m0 + r*16 + rb + j;
        float v = acc[r][c][j] + bv;
        if (MODE==0){
          if (col < 384) outb[(size_t)row*384 + col] = f2b(v);
          else {
            int bb = row/Lc; int l = row - bb*Lc;
            int nh = (col-384)>>5; int d = col&31;
            vdst[(((size_t)(bb*NHc+nh))*Lc + l)*DHc + d] = f2b(v);
          }
        } else if (MODE==1){
          outf[(size_t)row*Cc + col] = v + b2f(residb[(size_t)row*Cc + col]);
        } else if (MODE==2){
          float gv = 0.5f*v*(1.f + erff(v*0.70710678118654752f));
          outb[(size_t)row*HIDc + col] = f2b(gv);
        } else {
          outf[(size_t)row*Cc + col] = v + residf[(size_t)row*Cc + col];
        }
      }
    }
  }
}

// ---------------- rope + head reorder ----------------
__global__ __launch_bounds__(256) void rope_kernel(const u16* __restrict__ qk, const float* __restrict__ ct,
                                                   const float* __restrict__ st, u16* __restrict__ q_s, u16* __restrict__ k_s){
  int gid = blockIdx.x*256 + threadIdx.x;   // < ROWS*192 (one pair each)
  int pp = gid % 192; int row = gid / 192;
  int bb = row / Lc; int l = row - bb*Lc;
  bool isq = pp < 96; int p = isq ? pp : pp-96;
  int cbase = (isq ? 0 : 192) + 2*p;
  const u16* qr = qk + (size_t)row*384 + cbase;
  float re = b2f(qr[0]), im = b2f(qr[1]);
  float cs = ct[l*96+p], sn = st[l*96+p];
  float r2 = cs*re - sn*im;
  float i2 = sn*re + cs*im;
  if (isq){ r2 *= 0.1767766952966369f; i2 *= 0.1767766952966369f; }
  int nh = p>>4, d = (2*p)&31;
  u16* dst = (isq ? q_s : k_s) + (((size_t)(bb*NHc+nh))*Lc + l)*DHc + d;
  dst[0] = f2b(r2);
  dst[1] = f2b(i2);
}

// ---------------- phase A: per (head,chunk) solve -> U, -R, A'=-K^T R (frags), B=K^T U ----------------
__global__ __launch_bounds__(64) void ttta_kernel(const u16* __restrict__ k_s, const u16* __restrict__ v_s,
                                                  u16* __restrict__ u_s, u16* __restrict__ rn_s,
                                                  u16* __restrict__ af_s, u16* __restrict__ bc_s){
  __shared__ float Gl[1024];
  __shared__ u16 LK[32*40];
  __shared__ float LU[32*33];
  __shared__ float LR[32*33];
  int pair = blockIdx.x;
  int head = pair / NCHUNK;
  int l0 = (pair - head*NCHUNK) * Sc;
  int lane = threadIdx.x; int rr = lane&31; int hi = lane>>5; int ks = hi*8;
  const u16* kb = k_s + ((size_t)head*Lc + l0)*DHc;
  bf16x8 a0 = *(const bf16x8*)(kb + rr*32 + ks);        // K[rr][ks..ks+7]
  bf16x8 a1 = *(const bf16x8*)(kb + rr*32 + 16 + ks);   // K[rr][16+ks..]
  *(bf16x8*)(LK + rr*40 + ks) = a0;                     // LK[l][d] staging
  *(bf16x8*)(LK + rr*40 + 16 + ks) = a1;
  f32x16 g = zero16();
  g = __builtin_amdgcn_mfma_f32_32x32x16_bf16(a0, a0, g, 0,0,0);
  g = __builtin_amdgcn_mfma_f32_32x32x16_bf16(a1, a1, g, 0,0,0);
  #pragma unroll
  for (int reg=0;reg<16;reg++){
    int i = (reg&3) + 8*(reg>>2) + 4*hi;
    Gl[i*32 + rr] = ETAc * g[reg];
  }
  __syncthreads();
  float X[32];
  if (lane < 32){
    #pragma unroll
    for (int i=0;i<32;i++) X[i] = ETAc * b2f(v_s[((size_t)head*Lc + l0 + i)*DHc + lane]);
  } else {
    int m = lane-32;
    #pragma unroll
    for (int i=0;i<32;i++) X[i] = ETAc * b2f(kb[i*32 + m]);
  }
  #pragma unroll
  for (int i=1;i<32;i++){
    float a = X[i];
    #pragma unroll
    for (int j=0;j<i;j++) a -= Gl[i*32+j]*X[j];
    X[i] = a;
  }
  // global stores (U row-major, -R row-major) + LDS transposes (col-major staging)
  if (lane < 32){
    u16* dst = u_s + (size_t)pair*1024 + lane;
    #pragma unroll
    for (int i=0;i<32;i++) dst[i*32] = f2b(X[i]);
    #pragma unroll
    for (int i=0;i<32;i++) LU[lane*33 + i] = X[i];
  } else {
    u16* dst = rn_s + (size_t)pair*1024 + (lane&31);
    #pragma unroll
    for (int i=0;i<32;i++) dst[i*32] = f2b(-X[i]);
    #pragma unroll
    for (int i=0;i<32;i++) LR[(lane&31)*33 + i] = X[i];
  }
  __syncthreads();
  // column fragments: lane rr = col rr, slots l
  union { bf16x8 v; u16 s[8]; } kc1, kc2, uc1, uc2, rc1, rc2;
  #pragma unroll
  for (int s=0;s<8;s++){
    kc1.s[s] = LK[(ks+s)*40 + rr];
    kc2.s[s] = LK[(16+ks+s)*40 + rr];
    uc1.s[s] = f2b(LU[rr*33 + ks+s]);
    uc2.s[s] = f2b(LU[rr*33 + 16+ks+s]);
    rc1.s[s] = f2b(LR[rr*33 + ks+s]);
    rc2.s[s] = f2b(LR[rr*33 + 16+ks+s]);
  }
  // B = K^T U  (acc layout: lane=col j, regs=rows i)
  f32x16 bacc = zero16();
  bacc = __builtin_amdgcn_mfma_f32_32x32x16_bf16(kc1.v, uc1.v, bacc, 0,0,0);
  bacc = __builtin_amdgcn_mfma_f32_32x32x16_bf16(kc2.v, uc2.v, bacc, 0,0,0);
  union { bf16x8 v; u16 s[8]; } bo1, bo2;
  #pragma unroll
  for (int r=0;r<8;r++){ bo1.s[r] = f2b(bacc[r]); bo2.s[r] = f2b(bacc[8+r]); }
  *(bf16x8*)(bc_s + (size_t)pair*1024 + lane*16) = bo1.v;
  *(bf16x8*)(bc_s + (size_t)pair*1024 + lane*16 + 8) = bo2.v;
  // (R^T K): result[p][q]=sum_l R[l][p]K[l][q]; lane rr holds (K^T R) row rr over regs -> A' = -that
  f32x16 aacc = zero16();
  aacc = __builtin_amdgcn_mfma_f32_32x32x16_bf16(rc1.v, kc1.v, aacc, 0,0,0);
  aacc = __builtin_amdgcn_mfma_f32_32x32x16_bf16(rc2.v, kc2.v, aacc, 0,0,0);
  f32x16 an;
  #pragma unroll
  for (int r=0;r<16;r++) an[r] = -aacc[r];
  bf16x8 f1, f2;
  make_bfrags(an, hi, f1, f2);
  *(bf16x8*)(af_s + (size_t)pair*1024 + lane*16) = f1;
  *(bf16x8*)(af_s + (size_t)pair*1024 + lane*16 + 8) = f2;
}

// ---------------- phase B: MFMA affine scan  T_{c+1} = T_c + A'_c T_c + B_c ----------------
__global__ __launch_bounds__(64) void tttb_kernel(const u16* __restrict__ af_s, const u16* __restrict__ bc_s,
                                                  const float* __restrict__ W0, u16* __restrict__ w_snap){
  int head = blockIdx.x; int nh = head % NHc;
  int lane = threadIdx.x; int rr = lane&31; int hi = lane>>5;
  // T acc: lane rr holds T[i][rr] = W0[rr][i], i = (r&3)+8*(r>>2)+4*hi
  f32x16 T;
  const float* w0r = W0 + nh*1024 + rr*32 + 4*hi;
  #pragma unroll
  for (int q=0;q<4;q++){
    f32x4 v = *(const f32x4*)(w0r + 8*q);
    T[4*q+0]=v[0]; T[4*q+1]=v[1]; T[4*q+2]=v[2]; T[4*q+3]=v[3];
  }
  size_t hb = (size_t)head*NCHUNK;
  const bf16x8* afp = (const bf16x8*)(af_s + hb*1024);
  const bf16x8* bcp = (const bf16x8*)(bc_s + hb*1024);
  bf16x8 A1 = afp[lane*2], A2 = afp[lane*2+1];
  bf16x8 Bv1 = bcp[lane*2], Bv2 = bcp[lane*2+1];
  bf16x8 b1, b2;
  make_bfrags(T, hi, b1, b2);
  for (int c=0;c<NCHUNK;c++){
    bf16x8 nA1=A1, nA2=A2, nB1=Bv1, nB2=Bv2;
    if (c+1 < NCHUNK){
      int base = (c+1)*128 + lane*2;
      nA1 = afp[base]; nA2 = afp[base+1];
      nB1 = bcp[base]; nB2 = bcp[base+1];
    }
    // snapshot T_c (bf16, W row-major): b1/b2 hold T[.][rr] slices = W[rr][.]
    u16* wrow = w_snap + (hb + c)*1024 + rr*32;
    *(bf16x8*)(wrow + hi*8) = b1;
    *(bf16x8*)(wrow + 16 + hi*8) = b2;
    // acc = T + B
    f32x16 acc;
    #pragma unroll
    for (int r=0;r<8;r++){ acc[r] = T[r] + b2f((u16)Bv1[r]); acc[8+r] = T[8+r] + b2f((u16)Bv2[r]); }
    acc = __builtin_amdgcn_mfma_f32_32x32x16_bf16(A1, b1, acc, 0,0,0);
    acc = __builtin_amdgcn_mfma_f32_32x32x16_bf16(A2, b2, acc, 0,0,0);
    T = acc;
    make_bfrags(T, hi, b1, b2);
    A1=nA1; A2=nA2; Bv1=nB1; Bv2=nB2;
  }
}

// ---------------- phase C: O = Q*T0 + tril(Q K^T)*(U - R*T0) ----------------
__global__ __launch_bounds__(64) void tttc_kernel(const u16* __restrict__ q_s, const u16* __restrict__ k_s,
                                                  const u16* __restrict__ w_snap, const u16* __restrict__ u_s,
                                                  const u16* __restrict__ rn_s, u16* __restrict__ o_bf){
  __shared__ __align__(16) u16 Pl[32*40];
  int pair = blockIdx.x;
  int head = pair / NCHUNK;
  int ch = pair - head*NCHUNK;
  int l0 = ch*Sc;
  int lane = threadIdx.x; int rr = lane&31; int hi = lane>>5; int ks = hi*8;
  const u16* qb = q_s + ((size_t)head*Lc + l0)*DHc;
  const u16* kb = k_s + ((size_t)head*Lc + l0)*DHc;
  bf16x8 q0 = *(const bf16x8*)(qb + rr*32 + ks);
  bf16x8 q1 = *(const bf16x8*)(qb + rr*32 + 16 + ks);
  bf16x8 k0 = *(const bf16x8*)(kb + rr*32 + ks);
  bf16x8 k1 = *(const bf16x8*)(kb + rr*32 + 16 + ks);
  f32x16 p = zero16();
  p = __builtin_amdgcn_mfma_f32_32x32x16_bf16(q0, k0, p, 0,0,0);
  p = __builtin_amdgcn_mfma_f32_32x32x16_bf16(q1, k1, p, 0,0,0);
  #pragma unroll
  for (int reg=0;reg<16;reg++){
    int i = (reg&3)+8*(reg>>2)+4*hi;
    Pl[i*40+rr] = (rr<=i) ? f2b(p[reg]) : (u16)0;
  }
  // T0 fragments (b-form): w_snap row rr = W[rr][.] = T0[.][rr]
  const u16* wsb = w_snap + (size_t)pair*1024;
  bf16x8 tb0 = *(const bf16x8*)(wsb + rr*32 + ks);
  bf16x8 tb1 = *(const bf16x8*)(wsb + rr*32 + 16 + ks);
  // Wr = U - R*T0 : acc preload U[i][rr], then mfma with (-R) rows x T0 cols
  const u16* ub = u_s + (size_t)pair*1024;
  f32x16 wr;
  #pragma unroll
  for (int r=0;r<16;r++){
    int i = (r&3)+8*(r>>2)+4*hi;
    wr[r] = b2f(ub[i*32 + rr]);
  }
  const u16* rb = rn_s + (size_t)pair*1024;
  bf16x8 rn0 = *(const bf16x8*)(rb + rr*32 + ks);
  bf16x8 rn1 = *(const bf16x8*)(rb + rr*32 + 16 + ks);
  wr = __builtin_amdgcn_mfma_f32_32x32x16_bf16(rn0, tb0, wr, 0,0,0);
  wr = __builtin_amdgcn_mfma_f32_32x32x16_bf16(rn1, tb1, wr, 0,0,0);
  bf16x8 wb0, wb1;
  make_bfrags(wr, hi, wb0, wb1);
  __syncthreads();
  f32x16 o = zero16();
  o = __builtin_amdgcn_mfma_f32_32x32x16_bf16(q0, tb0, o, 0,0,0);
  o = __builtin_amdgcn_mfma_f32_32x32x16_bf16(q1, tb1, o, 0,0,0);
  bf16x8 pa0 = *(const bf16x8*)(Pl + rr*40 + ks);
  bf16x8 pa1 = *(const bf16x8*)(Pl + rr*40 + 16 + ks);
  o = __builtin_amdgcn_mfma_f32_32x32x16_bf16(pa0, wb0, o, 0,0,0);
  o = __builtin_amdgcn_mfma_f32_32x32x16_bf16(pa1, wb1, o, 0,0,0);
  int bb = head/NHc, nh = head - bb*NHc;
  #pragma unroll
  for (int reg=0;reg<16;reg++){
    int i = (reg&3)+8*(reg>>2)+4*hi;
    o_bf[((size_t)(bb*Lc + l0 + i))*Cc + nh*32 + rr] = f2b(o[reg]);
  }
}

// ---------------- MLP depthwise conv (HID=768) + gelu, 8 channels/thread ----------------
__global__ __launch_bounds__(256) void dwc_kernel(const u16* __restrict__ h1, const float* __restrict__ wt9,
                                                  const float* __restrict__ bs, u16* __restrict__ h2, int row0){
  int gid = blockIdx.x*256 + threadIdx.x;   // < GROUPROWS*96
  int cg = gid % 96; int lrow = gid / 96; int ch0 = cg*8;
  int row = row0 + lrow;
  int l = row % Lc; int h = l/Wcc, w = l - h*Wcc;
  const u16* hp = h1 + (size_t)lrow*HIDc + ch0;
  float acc[8];
  { f32x4 b0 = *(const f32x4*)(bs+ch0), b1v = *(const f32x4*)(bs+ch0+4);
    acc[0]=b0[0];acc[1]=b0[1];acc[2]=b0[2];acc[3]=b0[3];
    acc[4]=b1v[0];acc[5]=b1v[1];acc[6]=b1v[2];acc[7]=b1v[3]; }
  #pragma unroll
  for (int kh=0;kh<3;kh++){
    int hh = h+kh-1; if (hh<0 || hh>=Hc) continue;
    #pragma unroll
    for (int kw=0;kw<3;kw++){
      int ww = w+kw-1; if (ww<0 || ww>=Wcc) continue;
      bf16x8 iv = *(const bf16x8*)(hp + ((kh-1)*Wcc + (kw-1))*HIDc);
      const float* wp = wt9 + (kh*3+kw)*HIDc + ch0;
      f32x4 w0 = *(const f32x4*)wp, w1 = *(const f32x4*)(wp+4);
      acc[0] += b2f((u16)iv[0])*w0[0]; acc[1] += b2f((u16)iv[1])*w0[1];
      acc[2] += b2f((u16)iv[2])*w0[2]; acc[3] += b2f((u16)iv[3])*w0[3];
      acc[4] += b2f((u16)iv[4])*w1[0]; acc[5] += b2f((u16)iv[5])*w1[1];
      acc[6] += b2f((u16)iv[6])*w1[2]; acc[7] += b2f((u16)iv[7])*w1[3];
    }
  }
  bf16x8 cv = *(const bf16x8*)hp;
  union { bf16x8 v; u16 s[8]; } ov;
  #pragma unroll
  for (int j=0;j<8;j++){
    float v = b2f((u16)cv[j]) + acc[j];
    ov.s[j] = f2b(0.5f*v*(1.f + erff(v*0.70710678118654752f)));
  }
  *(bf16x8*)(h2 + (size_t)lrow*HIDc + ch0) = ov.v;
}

// ---------------- launch ----------------
extern "C" void kernel_launch(void* const* d_in, const int* in_sizes, int n_in,
                              void* d_out, int out_size, void* d_ws, size_t ws_size,
                              hipStream_t stream){
  const float* x     = (const float*)d_in[0];
  const float* cpe_w = (const float*)d_in[1];
  const float* cpe_b = (const float*)d_in[2];
  const float* n1_g  = (const float*)d_in[3];
  const float* n1_b  = (const float*)d_in[4];
  const float* qkv_w = (const float*)d_in[5];
  const float* qkv_b = (const float*)d_in[6];
  const float* W0    = (const float*)d_in[7];
  const float* proj_w= (const float*)d_in[8];
  const float* proj_b= (const float*)d_in[9];
  const float* n2_g  = (const float*)d_in[10];
  const float* n2_b  = (const float*)d_in[11];
  const float* fc1_w = (const float*)d_in[12];
  const float* fc1_b = (const float*)d_in[13];
  const float* dwc_w = (const float*)d_in[14];
  const float* dwc_b = (const float*)d_in[15];
  const float* fc2_w = (const float*)d_in[16];
  const float* fc2_b = (const float*)d_in[17];

  char* ws = (char*)d_ws;
  size_t off = 0;
  auto alloc = [&](size_t bytes)->char*{
    char* p = ws + off;
    off += (bytes + 255) & ~(size_t)255;
    return p;
  };
  // arena ~138 MB
  u16* wbqkv = (u16*)alloc((size_t)576*192*2);
  u16* wbproj= (u16*)alloc((size_t)192*192*2);
  u16* wbfc1 = (u16*)alloc((size_t)768*192*2);
  u16* wbfc2 = (u16*)alloc((size_t)192*768*2);
  float* dwt9 = (float*)alloc((size_t)9*HIDc*4);
  float* ctab = (float*)alloc((size_t)Lc*96*4);
  float* stab = (float*)alloc((size_t)Lc*96*4);
  u16* regA = (u16*)alloc((size_t)ROWS*Cc*2);       // x1 -> h1 group
  u16* regB = (u16*)alloc((size_t)ROWS*Cc*2);       // xn -> qs -> xn2
  u16* regD = (u16*)alloc((size_t)NHEAD*Lc*DHc*2);  // vs -> obf -> h2 group
  u16* regE = (u16*)alloc((size_t)NHEAD*Lc*DHc*2);  // ksb
  u16* rn_s = (u16*)alloc((size_t)NPAIR*1024*2);    // -R row-major
  u16* af_s = (u16*)alloc((size_t)NPAIR*1024*2);    // A' fragments
  u16* wsn  = (u16*)alloc((size_t)NPAIR*1024*2);    // T0 snapshots (W row-major)
  // d_out (38,535,168 B): qk -> [us | bc] -> x2/final
  u16* qk = (u16*)d_out;
  u16* us = (u16*)d_out;
  u16* bc = us + (size_t)NPAIR*1024;
  float* x2 = (float*)d_out;

  u16* x1 = regA;
  u16* xn = regB;
  u16* qs = regB;
  u16* xn2 = regB;
  u16* vs = regD;
  u16* obf = regD;
  u16* ksb = regE;

  cast_bf16_kernel<<<(576*192+255)/256,256,0,stream>>>(qkv_w, wbqkv, 576*192);
  cast_bf16_kernel<<<(192*192+255)/256,256,0,stream>>>(proj_w, wbproj, 192*192);
  cast_bf16_kernel<<<(768*192+255)/256,256,0,stream>>>(fc1_w, wbfc1, 768*192);
  cast_bf16_kernel<<<(192*768+255)/256,256,0,stream>>>(fc2_w, wbfc2, 192*768);
  dwt_kernel<<<(768*9+255)/256,256,0,stream>>>(dwc_w, dwt9);
  rope_tab_kernel<<<(Lc*96)/256,256,0,stream>>>(ctab, stab);

  cpe_kernel<<<ROWS,192,0,stream>>>(x, cpe_w, cpe_b, x1);
  ln_kernel<0><<<ROWS/4,256,0,stream>>>(x1, nullptr, n1_g, n1_b, xn);
  { dim3 g(ROWS/64, 3); gemm_kernel<0><<<g,256,0,stream>>>(xn, wbqkv, qkv_b, 192, nullptr, qk, vs, nullptr, nullptr); }
  rope_kernel<<<(ROWS*192)/256,256,0,stream>>>(qk, ctab, stab, qs, ksb);
  ttta_kernel<<<NPAIR,64,0,stream>>>(ksb, vs, us, rn_s, af_s, bc);
  tttb_kernel<<<NHEAD,64,0,stream>>>(af_s, bc, W0, wsn);
  tttc_kernel<<<NPAIR,64,0,stream>>>(qs, ksb, wsn, us, rn_s, obf);
  { dim3 g(ROWS/64, 1); gemm_kernel<1><<<g,256,0,stream>>>(obf, wbproj, proj_b, 192, x2, nullptr, nullptr, x1, nullptr); }
  ln_kernel<1><<<ROWS/4,256,0,stream>>>(nullptr, x2, n2_g, n2_b, xn2);
  for (int g4=0; g4<4; g4++){
    const u16* a_in = xn2 + (size_t)g4*GROUPROWS*Cc;
    u16* h1 = regA;
    u16* h2 = regD;
    float* xo = x2 + (size_t)g4*GROUPROWS*Cc;
    { dim3 g(GROUPROWS/64, 4); gemm_kernel<2><<<g,256,0,stream>>>(a_in, wbfc1, fc1_b, 192, nullptr, h1, nullptr, nullptr, nullptr); }
    dwc_kernel<<<(GROUPROWS*96)/256,256,0,stream>>>(h1, dwt9, dwc_b, h2, g4*GROUPROWS);
    { dim3 g(GROUPROWS/64, 1); gemm_kernel<3><<<g,256,0,stream>>>(h2, wbfc2, fc2_b, 768, xo, nullptr, nullptr, nullptr, xo); }
  }
}

// Round 5
// 597.082 us; speedup vs baseline: 1.6170x; 1.0741x over previous
//
#include <hip/hip_runtime.h>
#include <hip/hip_bf16.h>

#define Bc 16
#define Hc 56
#define Wcc 56
#define Cc 192
#define NHc 6
#define Lc 3136
#define DHc 32
#define HIDc 768
#define NHEAD 96          // B*NH
#define Sc 32             // chunk length
#define NCHUNK 98         // chunks per head (98*32 = 3136)
#define NPAIR (NHEAD*NCHUNK)
#define ROWS (Bc*Lc)      // 50176
#define GROUPROWS (ROWS/4)
#define ETAc (1.0f/32.0f)

typedef unsigned short u16;
typedef unsigned int u32;
typedef __attribute__((ext_vector_type(8))) short bf16x8;
typedef __attribute__((ext_vector_type(4))) float f32x4;
typedef __attribute__((ext_vector_type(16))) float f32x16;

__device__ __forceinline__ float b2f(u16 v){ u32 u = ((u32)v)<<16; float f; __builtin_memcpy(&f,&u,4); return f; }
__device__ __forceinline__ u16 f2b(float f){ u32 u; __builtin_memcpy(&u,&f,4); u32 r = u + 0x7FFFu + ((u>>16)&1u); return (u16)(r>>16); }
__device__ __forceinline__ f32x16 zero16(){ f32x16 z = {0,0,0,0,0,0,0,0,0,0,0,0,0,0,0,0}; return z; }

// Build b-operand (and a-operand; same layout) bf16 fragments from an f32 accumulator.
__device__ __forceinline__ void make_bfrags(const f32x16& t, int hi, bf16x8& b1, bf16x8& b2){
  u32 P[8], S[8];
  #pragma unroll
  for (int q=0;q<4;q++){
    #pragma unroll
    for (int j=0;j<2;j++){
      u32 r; float lo = t[4*q+2*j], hv = t[4*q+2*j+1];
      asm("v_cvt_pk_bf16_f32 %0, %1, %2" : "=v"(r) : "v"(lo), "v"(hv));
      P[2*q+j] = r;
    }
  }
  #pragma unroll
  for (int i=0;i<8;i++) S[i] = (u32)__shfl_xor((int)P[i], 32);
  union { u32 u[4]; bf16x8 v; } f1, f2;
  if (hi==0){ f1.u[0]=P[0]; f1.u[1]=P[1]; f1.u[2]=S[0]; f1.u[3]=S[1];
              f2.u[0]=P[4]; f2.u[1]=P[5]; f2.u[2]=S[4]; f2.u[3]=S[5]; }
  else      { f1.u[0]=S[2]; f1.u[1]=S[3]; f1.u[2]=P[2]; f1.u[3]=P[3];
              f2.u[0]=S[6]; f2.u[1]=S[7]; f2.u[2]=P[6]; f2.u[3]=P[7]; }
  b1 = f1.v; b2 = f2.v;
}

// ---------------- weight cast ----------------
__global__ __launch_bounds__(256) void cast_bf16_kernel(const float* __restrict__ src, u16* __restrict__ dst, int n){
  int i = blockIdx.x*256 + threadIdx.x;
  if (i < n) dst[i] = f2b(src[i]);
}

// ---------------- dw weight transpose: (CH,9) -> (9,CH) ----------------
__global__ __launch_bounds__(256) void dwt_kernel(const float* __restrict__ w, float* __restrict__ wt, int CH){
  int i = blockIdx.x*256 + threadIdx.x;
  if (i < CH*9){ int ch = i/9, t = i - ch*9; wt[t*CH + ch] = w[i]; }
}

// ---------------- rope tables ----------------
__global__ __launch_bounds__(256) void rope_tab_kernel(float* __restrict__ ct, float* __restrict__ st){
  int i = blockIdx.x*256 + threadIdx.x;   // < Lc*96
  int l = i/96, p = i - l*96;
  int h = l/Wcc, w = l - h*Wcc;
  int kk = (p<48)? p : p-48;
  float th = powf(10000.f, -(float)kk/48.f);
  float ang = (float)((p<48)? h : w) * th;
  ct[i] = cosf(ang);
  st[i] = sinf(ang);
}

// ---------------- CPE depthwise conv (C=192), 8 ch/thread, vectorized ----------------
__global__ __launch_bounds__(256) void cpe_kernel(const float* __restrict__ x, const float* __restrict__ cwt9,
                                                  const float* __restrict__ bs, u16* __restrict__ x1){
  int gid = blockIdx.x*256 + threadIdx.x;   // < ROWS*24
  int cg = gid % 24; int row = gid / 24; int ch0 = cg*8;
  int l = row % Lc; int h = l/Wcc, w = l - h*Wcc;
  const float* xp = x + (size_t)row*Cc + ch0;
  float acc[8];
  { f32x4 b0 = *(const f32x4*)(bs+ch0), b1v = *(const f32x4*)(bs+ch0+4);
    acc[0]=b0[0];acc[1]=b0[1];acc[2]=b0[2];acc[3]=b0[3];
    acc[4]=b1v[0];acc[5]=b1v[1];acc[6]=b1v[2];acc[7]=b1v[3]; }
  #pragma unroll
  for (int kh=0;kh<3;kh++){
    int hh = h+kh-1; if (hh<0 || hh>=Hc) continue;
    #pragma unroll
    for (int kw=0;kw<3;kw++){
      int ww = w+kw-1; if (ww<0 || ww>=Wcc) continue;
      const float* ip = xp + ((kh-1)*Wcc + (kw-1))*Cc;
      f32x4 i0 = *(const f32x4*)ip, i1 = *(const f32x4*)(ip+4);
      const float* wp = cwt9 + (kh*3+kw)*Cc + ch0;
      f32x4 w0 = *(const f32x4*)wp, w1 = *(const f32x4*)(wp+4);
      acc[0] += i0[0]*w0[0]; acc[1] += i0[1]*w0[1]; acc[2] += i0[2]*w0[2]; acc[3] += i0[3]*w0[3];
      acc[4] += i1[0]*w1[0]; acc[5] += i1[1]*w1[1]; acc[6] += i1[2]*w1[2]; acc[7] += i1[3]*w1[3];
    }
  }
  f32x4 c0 = *(const f32x4*)xp, c1 = *(const f32x4*)(xp+4);
  union { bf16x8 v; u16 s[8]; } ov;
  ov.s[0]=f2b(c0[0]+acc[0]); ov.s[1]=f2b(c0[1]+acc[1]); ov.s[2]=f2b(c0[2]+acc[2]); ov.s[3]=f2b(c0[3]+acc[3]);
  ov.s[4]=f2b(c1[0]+acc[4]); ov.s[5]=f2b(c1[1]+acc[5]); ov.s[6]=f2b(c1[2]+acc[6]); ov.s[7]=f2b(c1[3]+acc[7]);
  *(bf16x8*)(x1 + (size_t)row*Cc + ch0) = ov.v;
}

// ---------------- LayerNorm -> bf16.  INF32=0: bf16 input, 1: fp32 input ----------------
template<int INF32>
__global__ __launch_bounds__(256) void ln_kernel(const u16* __restrict__ xb, const float* __restrict__ xf,
                                                 const float* __restrict__ g, const float* __restrict__ b,
                                                 u16* __restrict__ out){
  int row = blockIdx.x*4 + (threadIdx.x>>6);
  int lane = threadIdx.x & 63;
  float v0, v1, v2;
  if (INF32){
    const float* xr = xf + (size_t)row*Cc;
    v0 = xr[lane]; v1 = xr[lane+64]; v2 = xr[lane+128];
  } else {
    const u16* xr = xb + (size_t)row*Cc;
    v0 = b2f(xr[lane]); v1 = b2f(xr[lane+64]); v2 = b2f(xr[lane+128]);
  }
  float s = v0+v1+v2;
  float q = v0*v0 + v1*v1 + v2*v2;
  #pragma unroll
  for (int off=32; off; off>>=1){ s += __shfl_xor(s, off); q += __shfl_xor(q, off); }
  float mu = s*(1.f/Cc);
  float var = q*(1.f/Cc) - mu*mu;
  float rs = rsqrtf(var + 1e-5f);
  u16* orow = out + (size_t)row*Cc;
  orow[lane]     = f2b((v0-mu)*rs*g[lane]     + b[lane]);
  orow[lane+64]  = f2b((v1-mu)*rs*g[lane+64]  + b[lane+64]);
  orow[lane+128] = f2b((v2-mu)*rs*g[lane+128] + b[lane+128]);
}

// ---------------- generic GEMM ----------------
template<int MODE>
__global__ __launch_bounds__(256) void gemm_kernel(
    const u16* __restrict__ A, const u16* __restrict__ Wt,
    const float* __restrict__ bias, int K,
    float* __restrict__ outf, u16* __restrict__ outb,
    u16* __restrict__ vdst, const u16* __restrict__ residb, const float* __restrict__ residf)
{
  int wid = threadIdx.x>>6, lane = threadIdx.x&63;
  int m0 = blockIdx.x*64 + (wid>>1)*32;
  int n0 = blockIdx.y*192 + (wid&1)*96;
  int ar = lane&15, kg = (lane>>4)*8;
  f32x4 acc[2][6];
  #pragma unroll
  for (int r=0;r<2;r++)
    #pragma unroll
    for (int c=0;c<6;c++){ f32x4 z = {0.f,0.f,0.f,0.f}; acc[r][c] = z; }
  for (int k0=0;k0<K;k0+=32){
    bf16x8 af[2], bfr[6];
    #pragma unroll
    for (int r=0;r<2;r++) af[r] = *(const bf16x8*)(A + (size_t)(m0 + r*16 + ar)*K + k0 + kg);
    #pragma unroll
    for (int c=0;c<6;c++) bfr[c] = *(const bf16x8*)(Wt + (size_t)(n0 + c*16 + ar)*K + k0 + kg);
    #pragma unroll
    for (int r=0;r<2;r++)
      #pragma unroll
      for (int c=0;c<6;c++)
        acc[r][c] = __builtin_amdgcn_mfma_f32_16x16x32_bf16(af[r], bfr[c], acc[r][c], 0,0,0);
  }
  int rb = (lane>>4)*4;
  #pragma unroll
  for (int r=0;r<2;r++){
    #pragma unroll
    for (int c=0;c<6;c++){
      int col = n0 + c*16 + ar;
      float bv = bias[col];
      #pragma unroll
      for (int j=0;j<4;j++){
        int row = m0 + r*16 + rb + j;
        float v = acc[r][c][j] + bv;
        if (MODE==0){
          if (col < 384) outb[(size_t)row*384 + col] = f2b(v);
          else {
            int bb = row/Lc; int l = row - bb*Lc;
            int nh = (col-384)>>5; int d = col&31;
            vdst[(((size_t)(bb*NHc+nh))*Lc + l)*DHc + d] = f2b(v);
          }
        } else if (MODE==1){
          outf[(size_t)row*Cc + col] = v + b2f(residb[(size_t)row*Cc + col]);
        } else if (MODE==2){
          float gv = 0.5f*v*(1.f + erff(v*0.70710678118654752f));
          outb[(size_t)row*HIDc + col] = f2b(gv);
        } else {
          outf[(size_t)row*Cc + col] = v + residf[(size_t)row*Cc + col];
        }
      }
    }
  }
}

// ---------------- rope + head reorder, 8 pairs/thread vectorized ----------------
__global__ __launch_bounds__(256) void rope_kernel(const u16* __restrict__ qk, const float* __restrict__ ct,
                                                   const float* __restrict__ st, u16* __restrict__ q_s, u16* __restrict__ k_s){
  int gid = blockIdx.x*256 + threadIdx.x;   // < ROWS*24
  int sub = gid % 24; int row = gid / 24;
  int bb = row / Lc; int l = row - bb*Lc;
  bool isq = sub < 12; int pg = isq ? sub : sub-12;
  int p0 = pg*8;                      // pair index base (8 pairs)
  int cbase = (isq ? 0 : 192) + 2*p0; // 16 contiguous u16
  const u16* qr = qk + (size_t)row*384 + cbase;
  bf16x8 in0 = *(const bf16x8*)qr;
  bf16x8 in1 = *(const bf16x8*)(qr + 8);
  const float* cp = ct + l*96 + p0;
  const float* sp = st + l*96 + p0;
  f32x4 c0 = *(const f32x4*)cp, c1 = *(const f32x4*)(cp+4);
  f32x4 s0 = *(const f32x4*)sp, s1 = *(const f32x4*)(sp+4);
  float cs[8] = {c0[0],c0[1],c0[2],c0[3],c1[0],c1[1],c1[2],c1[3]};
  float sn[8] = {s0[0],s0[1],s0[2],s0[3],s1[0],s1[1],s1[2],s1[3]};
  float sc = isq ? 0.1767766952966369f : 1.0f;
  union { bf16x8 v; u16 s[8]; } o0, o1;
  #pragma unroll
  for (int j=0;j<4;j++){
    float re = b2f((u16)in0[2*j]), im = b2f((u16)in0[2*j+1]);
    o0.s[2*j]   = f2b((cs[j]*re - sn[j]*im)*sc);
    o0.s[2*j+1] = f2b((sn[j]*re + cs[j]*im)*sc);
  }
  #pragma unroll
  for (int j=0;j<4;j++){
    float re = b2f((u16)in1[2*j]), im = b2f((u16)in1[2*j+1]);
    o1.s[2*j]   = f2b((cs[4+j]*re - sn[4+j]*im)*sc);
    o1.s[2*j+1] = f2b((sn[4+j]*re + cs[4+j]*im)*sc);
  }
  int nh = pg>>1, d0 = (pg&1)*16;
  u16* dst = (isq ? q_s : k_s) + (((size_t)(bb*NHc+nh))*Lc + l)*DHc + d0;
  *(bf16x8*)dst = o0.v;
  *(bf16x8*)(dst+8) = o1.v;
}

// ---------------- phase A: per (head,chunk) solve -> U, -R, A'=-K^T R (frags), B=K^T U ----------------
__global__ __launch_bounds__(64) void ttta_kernel(const u16* __restrict__ k_s, const u16* __restrict__ v_s,
                                                  u16* __restrict__ u_s, u16* __restrict__ rn_s,
                                                  u16* __restrict__ af_s, u16* __restrict__ bc_s){
  __shared__ float Gl[1024];
  __shared__ u16 LK[32*40];
  __shared__ float LU[32*33];
  __shared__ float LR[32*33];
  int pair = blockIdx.x;
  int head = pair / NCHUNK;
  int l0 = (pair - head*NCHUNK) * Sc;
  int lane = threadIdx.x; int rr = lane&31; int hi = lane>>5; int ks = hi*8;
  const u16* kb = k_s + ((size_t)head*Lc + l0)*DHc;
  bf16x8 a0 = *(const bf16x8*)(kb + rr*32 + ks);
  bf16x8 a1 = *(const bf16x8*)(kb + rr*32 + 16 + ks);
  *(bf16x8*)(LK + rr*40 + ks) = a0;
  *(bf16x8*)(LK + rr*40 + 16 + ks) = a1;
  f32x16 g = zero16();
  g = __builtin_amdgcn_mfma_f32_32x32x16_bf16(a0, a0, g, 0,0,0);
  g = __builtin_amdgcn_mfma_f32_32x32x16_bf16(a1, a1, g, 0,0,0);
  #pragma unroll
  for (int reg=0;reg<16;reg++){
    int i = (reg&3) + 8*(reg>>2) + 4*hi;
    Gl[i*32 + rr] = ETAc * g[reg];
  }
  __syncthreads();
  float X[32];
  if (lane < 32){
    #pragma unroll
    for (int i=0;i<32;i++) X[i] = ETAc * b2f(v_s[((size_t)head*Lc + l0 + i)*DHc + lane]);
  } else {
    int m = lane-32;
    #pragma unroll
    for (int i=0;i<32;i++) X[i] = ETAc * b2f(kb[i*32 + m]);
  }
  #pragma unroll
  for (int i=1;i<32;i++){
    float a = X[i];
    #pragma unroll
    for (int j=0;j<i;j++) a -= Gl[i*32+j]*X[j];
    X[i] = a;
  }
  if (lane < 32){
    u16* dst = u_s + (size_t)pair*1024 + lane;
    #pragma unroll
    for (int i=0;i<32;i++) dst[i*32] = f2b(X[i]);
    #pragma unroll
    for (int i=0;i<32;i++) LU[lane*33 + i] = X[i];
  } else {
    u16* dst = rn_s + (size_t)pair*1024 + (lane&31);
    #pragma unroll
    for (int i=0;i<32;i++) dst[i*32] = f2b(-X[i]);
    #pragma unroll
    for (int i=0;i<32;i++) LR[(lane&31)*33 + i] = X[i];
  }
  __syncthreads();
  union { bf16x8 v; u16 s[8]; } kc1, kc2, uc1, uc2, rc1, rc2;
  #pragma unroll
  for (int s=0;s<8;s++){
    kc1.s[s] = LK[(ks+s)*40 + rr];
    kc2.s[s] = LK[(16+ks+s)*40 + rr];
    uc1.s[s] = f2b(LU[rr*33 + ks+s]);
    uc2.s[s] = f2b(LU[rr*33 + 16+ks+s]);
    rc1.s[s] = f2b(LR[rr*33 + ks+s]);
    rc2.s[s] = f2b(LR[rr*33 + 16+ks+s]);
  }
  f32x16 bacc = zero16();
  bacc = __builtin_amdgcn_mfma_f32_32x32x16_bf16(kc1.v, uc1.v, bacc, 0,0,0);
  bacc = __builtin_amdgcn_mfma_f32_32x32x16_bf16(kc2.v, uc2.v, bacc, 0,0,0);
  union { bf16x8 v; u16 s[8]; } bo1, bo2;
  #pragma unroll
  for (int r=0;r<8;r++){ bo1.s[r] = f2b(bacc[r]); bo2.s[r] = f2b(bacc[8+r]); }
  *(bf16x8*)(bc_s + (size_t)pair*1024 + lane*16) = bo1.v;
  *(bf16x8*)(bc_s + (size_t)pair*1024 + lane*16 + 8) = bo2.v;
  f32x16 aacc = zero16();
  aacc = __builtin_amdgcn_mfma_f32_32x32x16_bf16(rc1.v, kc1.v, aacc, 0,0,0);
  aacc = __builtin_amdgcn_mfma_f32_32x32x16_bf16(rc2.v, kc2.v, aacc, 0,0,0);
  f32x16 an;
  #pragma unroll
  for (int r=0;r<16;r++) an[r] = -aacc[r];
  bf16x8 f1, f2;
  make_bfrags(an, hi, f1, f2);
  *(bf16x8*)(af_s + (size_t)pair*1024 + lane*16) = f1;
  *(bf16x8*)(af_s + (size_t)pair*1024 + lane*16 + 8) = f2;
}

// ---------------- phase B: MFMA affine scan  T_{c+1} = T_c + A'_c T_c + B_c ----------------
__global__ __launch_bounds__(64) void tttb_kernel(const u16* __restrict__ af_s, const u16* __restrict__ bc_s,
                                                  const float* __restrict__ W0, u16* __restrict__ w_snap){
  int head = blockIdx.x; int nh = head % NHc;
  int lane = threadIdx.x; int rr = lane&31; int hi = lane>>5;
  f32x16 T;
  const float* w0r = W0 + nh*1024 + rr*32 + 4*hi;
  #pragma unroll
  for (int q=0;q<4;q++){
    f32x4 v = *(const f32x4*)(w0r + 8*q);
    T[4*q+0]=v[0]; T[4*q+1]=v[1]; T[4*q+2]=v[2]; T[4*q+3]=v[3];
  }
  size_t hb = (size_t)head*NCHUNK;
  const bf16x8* afp = (const bf16x8*)(af_s + hb*1024);
  const bf16x8* bcp = (const bf16x8*)(bc_s + hb*1024);
  bf16x8 A1 = afp[lane*2], A2 = afp[lane*2+1];
  bf16x8 Bv1 = bcp[lane*2], Bv2 = bcp[lane*2+1];
  bf16x8 b1, b2;
  make_bfrags(T, hi, b1, b2);
  for (int c=0;c<NCHUNK;c++){
    bf16x8 nA1=A1, nA2=A2, nB1=Bv1, nB2=Bv2;
    if (c+1 < NCHUNK){
      int base = (c+1)*128 + lane*2;
      nA1 = afp[base]; nA2 = afp[base+1];
      nB1 = bcp[base]; nB2 = bcp[base+1];
    }
    u16* wrow = w_snap + (hb + c)*1024 + rr*32;
    *(bf16x8*)(wrow + hi*8) = b1;
    *(bf16x8*)(wrow + 16 + hi*8) = b2;
    f32x16 acc;
    #pragma unroll
    for (int r=0;r<8;r++){ acc[r] = T[r] + b2f((u16)Bv1[r]); acc[8+r] = T[8+r] + b2f((u16)Bv2[r]); }
    acc = __builtin_amdgcn_mfma_f32_32x32x16_bf16(A1, b1, acc, 0,0,0);
    acc = __builtin_amdgcn_mfma_f32_32x32x16_bf16(A2, b2, acc, 0,0,0);
    T = acc;
    make_bfrags(T, hi, b1, b2);
    A1=nA1; A2=nA2; Bv1=nB1; Bv2=nB2;
  }
}

// ---------------- phase C: O = Q*T0 + tril(Q K^T)*(U - R*T0) ----------------
__global__ __launch_bounds__(64) void tttc_kernel(const u16* __restrict__ q_s, const u16* __restrict__ k_s,
                                                  const u16* __restrict__ w_snap, const u16* __restrict__ u_s,
                                                  const u16* __restrict__ rn_s, u16* __restrict__ o_bf){
  __shared__ __align__(16) u16 Pl[32*40];
  int pair = blockIdx.x;
  int head = pair / NCHUNK;
  int ch = pair - head*NCHUNK;
  int l0 = ch*Sc;
  int lane = threadIdx.x; int rr = lane&31; int hi = lane>>5; int ks = hi*8;
  const u16* qb = q_s + ((size_t)head*Lc + l0)*DHc;
  const u16* kb = k_s + ((size_t)head*Lc + l0)*DHc;
  bf16x8 q0 = *(const bf16x8*)(qb + rr*32 + ks);
  bf16x8 q1 = *(const bf16x8*)(qb + rr*32 + 16 + ks);
  bf16x8 k0 = *(const bf16x8*)(kb + rr*32 + ks);
  bf16x8 k1 = *(const bf16x8*)(kb + rr*32 + 16 + ks);
  f32x16 p = zero16();
  p = __builtin_amdgcn_mfma_f32_32x32x16_bf16(q0, k0, p, 0,0,0);
  p = __builtin_amdgcn_mfma_f32_32x32x16_bf16(q1, k1, p, 0,0,0);
  #pragma unroll
  for (int reg=0;reg<16;reg++){
    int i = (reg&3)+8*(reg>>2)+4*hi;
    Pl[i*40+rr] = (rr<=i) ? f2b(p[reg]) : (u16)0;
  }
  const u16* wsb = w_snap + (size_t)pair*1024;
  bf16x8 tb0 = *(const bf16x8*)(wsb + rr*32 + ks);
  bf16x8 tb1 = *(const bf16x8*)(wsb + rr*32 + 16 + ks);
  const u16* ub = u_s + (size_t)pair*1024;
  f32x16 wr;
  #pragma unroll
  for (int r=0;r<16;r++){
    int i = (r&3)+8*(r>>2)+4*hi;
    wr[r] = b2f(ub[i*32 + rr]);
  }
  const u16* rb = rn_s + (size_t)pair*1024;
  bf16x8 rn0 = *(const bf16x8*)(rb + rr*32 + ks);
  bf16x8 rn1 = *(const bf16x8*)(rb + rr*32 + 16 + ks);
  wr = __builtin_amdgcn_mfma_f32_32x32x16_bf16(rn0, tb0, wr, 0,0,0);
  wr = __builtin_amdgcn_mfma_f32_32x32x16_bf16(rn1, tb1, wr, 0,0,0);
  bf16x8 wb0, wb1;
  make_bfrags(wr, hi, wb0, wb1);
  __syncthreads();
  f32x16 o = zero16();
  o = __builtin_amdgcn_mfma_f32_32x32x16_bf16(q0, tb0, o, 0,0,0);
  o = __builtin_amdgcn_mfma_f32_32x32x16_bf16(q1, tb1, o, 0,0,0);
  bf16x8 pa0 = *(const bf16x8*)(Pl + rr*40 + ks);
  bf16x8 pa1 = *(const bf16x8*)(Pl + rr*40 + 16 + ks);
  o = __builtin_amdgcn_mfma_f32_32x32x16_bf16(pa0, wb0, o, 0,0,0);
  o = __builtin_amdgcn_mfma_f32_32x32x16_bf16(pa1, wb1, o, 0,0,0);
  int bb = head/NHc, nh = head - bb*NHc;
  #pragma unroll
  for (int reg=0;reg<16;reg++){
    int i = (reg&3)+8*(reg>>2)+4*hi;
    o_bf[((size_t)(bb*Lc + l0 + i))*Cc + nh*32 + rr] = f2b(o[reg]);
  }
}

// ---------------- MLP depthwise conv (HID=768) + gelu, 8 channels/thread ----------------
__global__ __launch_bounds__(256) void dwc_kernel(const u16* __restrict__ h1, const float* __restrict__ wt9,
                                                  const float* __restrict__ bs, u16* __restrict__ h2, int row0){
  int gid = blockIdx.x*256 + threadIdx.x;   // < GROUPROWS*96
  int cg = gid % 96; int lrow = gid / 96; int ch0 = cg*8;
  int row = row0 + lrow;
  int l = row % Lc; int h = l/Wcc, w = l - h*Wcc;
  const u16* hp = h1 + (size_t)lrow*HIDc + ch0;
  float acc[8];
  { f32x4 b0 = *(const f32x4*)(bs+ch0), b1v = *(const f32x4*)(bs+ch0+4);
    acc[0]=b0[0];acc[1]=b0[1];acc[2]=b0[2];acc[3]=b0[3];
    acc[4]=b1v[0];acc[5]=b1v[1];acc[6]=b1v[2];acc[7]=b1v[3]; }
  #pragma unroll
  for (int kh=0;kh<3;kh++){
    int hh = h+kh-1; if (hh<0 || hh>=Hc) continue;
    #pragma unroll
    for (int kw=0;kw<3;kw++){
      int ww = w+kw-1; if (ww<0 || ww>=Wcc) continue;
      bf16x8 iv = *(const bf16x8*)(hp + ((kh-1)*Wcc + (kw-1))*HIDc);
      const float* wp = wt9 + (kh*3+kw)*HIDc + ch0;
      f32x4 w0 = *(const f32x4*)wp, w1 = *(const f32x4*)(wp+4);
      acc[0] += b2f((u16)iv[0])*w0[0]; acc[1] += b2f((u16)iv[1])*w0[1];
      acc[2] += b2f((u16)iv[2])*w0[2]; acc[3] += b2f((u16)iv[3])*w0[3];
      acc[4] += b2f((u16)iv[4])*w1[0]; acc[5] += b2f((u16)iv[5])*w1[1];
      acc[6] += b2f((u16)iv[6])*w1[2]; acc[7] += b2f((u16)iv[7])*w1[3];
    }
  }
  bf16x8 cv = *(const bf16x8*)hp;
  union { bf16x8 v; u16 s[8]; } ov;
  #pragma unroll
  for (int j=0;j<8;j++){
    float v = b2f((u16)cv[j]) + acc[j];
    ov.s[j] = f2b(0.5f*v*(1.f + erff(v*0.70710678118654752f)));
  }
  *(bf16x8*)(h2 + (size_t)lrow*HIDc + ch0) = ov.v;
}

// ---------------- launch ----------------
extern "C" void kernel_launch(void* const* d_in, const int* in_sizes, int n_in,
                              void* d_out, int out_size, void* d_ws, size_t ws_size,
                              hipStream_t stream){
  const float* x     = (const float*)d_in[0];
  const float* cpe_w = (const float*)d_in[1];
  const float* cpe_b = (const float*)d_in[2];
  const float* n1_g  = (const float*)d_in[3];
  const float* n1_b  = (const float*)d_in[4];
  const float* qkv_w = (const float*)d_in[5];
  const float* qkv_b = (const float*)d_in[6];
  const float* W0    = (const float*)d_in[7];
  const float* proj_w= (const float*)d_in[8];
  const float* proj_b= (const float*)d_in[9];
  const float* n2_g  = (const float*)d_in[10];
  const float* n2_b  = (const float*)d_in[11];
  const float* fc1_w = (const float*)d_in[12];
  const float* fc1_b = (const float*)d_in[13];
  const float* dwc_w = (const float*)d_in[14];
  const float* dwc_b = (const float*)d_in[15];
  const float* fc2_w = (const float*)d_in[16];
  const float* fc2_b = (const float*)d_in[17];

  char* ws = (char*)d_ws;
  size_t off = 0;
  auto alloc = [&](size_t bytes)->char*{
    char* p = ws + off;
    off += (bytes + 255) & ~(size_t)255;
    return p;
  };
  u16* wbqkv = (u16*)alloc((size_t)576*192*2);
  u16* wbproj= (u16*)alloc((size_t)192*192*2);
  u16* wbfc1 = (u16*)alloc((size_t)768*192*2);
  u16* wbfc2 = (u16*)alloc((size_t)192*768*2);
  float* dwt9 = (float*)alloc((size_t)9*HIDc*4);
  float* cwt9 = (float*)alloc((size_t)9*Cc*4);
  float* ctab = (float*)alloc((size_t)Lc*96*4);
  float* stab = (float*)alloc((size_t)Lc*96*4);
  u16* regA = (u16*)alloc((size_t)ROWS*Cc*2);       // x1 -> h1 group
  u16* regB = (u16*)alloc((size_t)ROWS*Cc*2);       // xn -> qs -> xn2
  u16* regD = (u16*)alloc((size_t)NHEAD*Lc*DHc*2);  // vs -> obf -> h2 group
  u16* regE = (u16*)alloc((size_t)NHEAD*Lc*DHc*2);  // ksb
  u16* rn_s = (u16*)alloc((size_t)NPAIR*1024*2);    // -R row-major
  u16* af_s = (u16*)alloc((size_t)NPAIR*1024*2);    // A' fragments
  u16* wsn  = (u16*)alloc((size_t)NPAIR*1024*2);    // T0 snapshots (W row-major)
  // d_out: qk -> [us | bc] -> x2/final
  u16* qk = (u16*)d_out;
  u16* us = (u16*)d_out;
  u16* bc = us + (size_t)NPAIR*1024;
  float* x2 = (float*)d_out;

  u16* x1 = regA;
  u16* xn = regB;
  u16* qs = regB;
  u16* xn2 = regB;
  u16* vs = regD;
  u16* obf = regD;
  u16* ksb = regE;

  cast_bf16_kernel<<<(576*192+255)/256,256,0,stream>>>(qkv_w, wbqkv, 576*192);
  cast_bf16_kernel<<<(192*192+255)/256,256,0,stream>>>(proj_w, wbproj, 192*192);
  cast_bf16_kernel<<<(768*192+255)/256,256,0,stream>>>(fc1_w, wbfc1, 768*192);
  cast_bf16_kernel<<<(192*768+255)/256,256,0,stream>>>(fc2_w, wbfc2, 192*768);
  dwt_kernel<<<(768*9+255)/256,256,0,stream>>>(dwc_w, dwt9, HIDc);
  dwt_kernel<<<(192*9+255)/256,256,0,stream>>>(cpe_w, cwt9, Cc);
  rope_tab_kernel<<<(Lc*96)/256,256,0,stream>>>(ctab, stab);

  cpe_kernel<<<(ROWS*24)/256,256,0,stream>>>(x, cwt9, cpe_b, x1);
  ln_kernel<0><<<ROWS/4,256,0,stream>>>(x1, nullptr, n1_g, n1_b, xn);
  { dim3 g(ROWS/64, 3); gemm_kernel<0><<<g,256,0,stream>>>(xn, wbqkv, qkv_b, 192, nullptr, qk, vs, nullptr, nullptr); }
  rope_kernel<<<(ROWS*24)/256,256,0,stream>>>(qk, ctab, stab, qs, ksb);
  ttta_kernel<<<NPAIR,64,0,stream>>>(ksb, vs, us, rn_s, af_s, bc);
  tttb_kernel<<<NHEAD,64,0,stream>>>(af_s, bc, W0, wsn);
  tttc_kernel<<<NPAIR,64,0,stream>>>(qs, ksb, wsn, us, rn_s, obf);
  { dim3 g(ROWS/64, 1); gemm_kernel<1><<<g,256,0,stream>>>(obf, wbproj, proj_b, 192, x2, nullptr, nullptr, x1, nullptr); }
  ln_kernel<1><<<ROWS/4,256,0,stream>>>(nullptr, x2, n2_g, n2_b, xn2);
  for (int g4=0; g4<4; g4++){
    const u16* a_in = xn2 + (size_t)g4*GROUPROWS*Cc;
    u16* h1 = regA;
    u16* h2 = regD;
    float* xo = x2 + (size_t)g4*GROUPROWS*Cc;
    { dim3 g(GROUPROWS/64, 4); gemm_kernel<2><<<g,256,0,stream>>>(a_in, wbfc1, fc1_b, 192, nullptr, h1, nullptr, nullptr, nullptr); }
    dwc_kernel<<<(GROUPROWS*96)/256,256,0,stream>>>(h1, dwt9, dwc_b, h2, g4*GROUPROWS);
    { dim3 g(GROUPROWS/64, 1); gemm_kernel<3><<<g,256,0,stream>>>(h2, wbfc2, fc2_b, 768, xo, nullptr, nullptr, nullptr, xo); }
  }
}

// Round 6
// 553.588 us; speedup vs baseline: 1.7440x; 1.0786x over previous
//
#include <hip/hip_runtime.h>
#include <hip/hip_bf16.h>

#define Bc 16
#define Hc 56
#define Wcc 56
#define Cc 192
#define NHc 6
#define Lc 3136
#define DHc 32
#define HIDc 768
#define NHEAD 96          // B*NH
#define Sc 32             // chunk length
#define NCHUNK 98         // chunks per head (98*32 = 3136)
#define NPAIR (NHEAD*NCHUNK)
#define ROWS (Bc*Lc)      // 50176
#define GR2 (ROWS/2)      // 25088 rows per MLP group (8 images)
#define ETAc (1.0f/32.0f)

typedef unsigned short u16;
typedef unsigned int u32;
typedef __attribute__((ext_vector_type(8))) short bf16x8;
typedef __attribute__((ext_vector_type(4))) float f32x4;
typedef __attribute__((ext_vector_type(16))) float f32x16;

__device__ __forceinline__ float b2f(u16 v){ u32 u = ((u32)v)<<16; float f; __builtin_memcpy(&f,&u,4); return f; }
__device__ __forceinline__ u16 f2b(float f){ u32 u; __builtin_memcpy(&u,&f,4); u32 r = u + 0x7FFFu + ((u>>16)&1u); return (u16)(r>>16); }
__device__ __forceinline__ f32x16 zero16(){ f32x16 z = {0,0,0,0,0,0,0,0,0,0,0,0,0,0,0,0}; return z; }

// Build b-operand (and a-operand; same layout) bf16 fragments from an f32 accumulator.
__device__ __forceinline__ void make_bfrags(const f32x16& t, int hi, bf16x8& b1, bf16x8& b2){
  u32 P[8], S[8];
  #pragma unroll
  for (int q=0;q<4;q++){
    #pragma unroll
    for (int j=0;j<2;j++){
      u32 r; float lo = t[4*q+2*j], hv = t[4*q+2*j+1];
      asm("v_cvt_pk_bf16_f32 %0, %1, %2" : "=v"(r) : "v"(lo), "v"(hv));
      P[2*q+j] = r;
    }
  }
  #pragma unroll
  for (int i=0;i<8;i++) S[i] = (u32)__shfl_xor((int)P[i], 32);
  union { u32 u[4]; bf16x8 v; } f1, f2;
  if (hi==0){ f1.u[0]=P[0]; f1.u[1]=P[1]; f1.u[2]=S[0]; f1.u[3]=S[1];
              f2.u[0]=P[4]; f2.u[1]=P[5]; f2.u[2]=S[4]; f2.u[3]=S[5]; }
  else      { f1.u[0]=S[2]; f1.u[1]=S[3]; f1.u[2]=P[2]; f1.u[3]=P[3];
              f2.u[0]=S[6]; f2.u[1]=S[7]; f2.u[2]=P[6]; f2.u[3]=P[7]; }
  b1 = f1.v; b2 = f2.v;
}

// ---------------- weight cast ----------------
__global__ __launch_bounds__(256) void cast_bf16_kernel(const float* __restrict__ src, u16* __restrict__ dst, int n){
  int i = blockIdx.x*256 + threadIdx.x;
  if (i < n) dst[i] = f2b(src[i]);
}

// ---------------- dw weight transpose: (CH,9) -> (9,CH) ----------------
__global__ __launch_bounds__(256) void dwt_kernel(const float* __restrict__ w, float* __restrict__ wt, int CH){
  int i = blockIdx.x*256 + threadIdx.x;
  if (i < CH*9){ int ch = i/9, t = i - ch*9; wt[t*CH + ch] = w[i]; }
}

// ---------------- rope tables ----------------
__global__ __launch_bounds__(256) void rope_tab_kernel(float* __restrict__ ct, float* __restrict__ st){
  int i = blockIdx.x*256 + threadIdx.x;   // < Lc*96
  int l = i/96, p = i - l*96;
  int h = l/Wcc, w = l - h*Wcc;
  int kk = (p<48)? p : p-48;
  float th = powf(10000.f, -(float)kk/48.f);
  float ang = (float)((p<48)? h : w) * th;
  ct[i] = cosf(ang);
  st[i] = sinf(ang);
}

// ---------------- CPE depthwise conv (C=192), 8 ch/thread, vectorized ----------------
__global__ __launch_bounds__(256) void cpe_kernel(const float* __restrict__ x, const float* __restrict__ cwt9,
                                                  const float* __restrict__ bs, u16* __restrict__ x1){
  int gid = blockIdx.x*256 + threadIdx.x;   // < ROWS*24
  int cg = gid % 24; int row = gid / 24; int ch0 = cg*8;
  int l = row % Lc; int h = l/Wcc, w = l - h*Wcc;
  const float* xp = x + (size_t)row*Cc + ch0;
  float acc[8];
  { f32x4 b0 = *(const f32x4*)(bs+ch0), b1v = *(const f32x4*)(bs+ch0+4);
    acc[0]=b0[0];acc[1]=b0[1];acc[2]=b0[2];acc[3]=b0[3];
    acc[4]=b1v[0];acc[5]=b1v[1];acc[6]=b1v[2];acc[7]=b1v[3]; }
  #pragma unroll
  for (int kh=0;kh<3;kh++){
    int hh = h+kh-1; if (hh<0 || hh>=Hc) continue;
    #pragma unroll
    for (int kw=0;kw<3;kw++){
      int ww = w+kw-1; if (ww<0 || ww>=Wcc) continue;
      const float* ip = xp + ((kh-1)*Wcc + (kw-1))*Cc;
      f32x4 i0 = *(const f32x4*)ip, i1 = *(const f32x4*)(ip+4);
      const float* wp = cwt9 + (kh*3+kw)*Cc + ch0;
      f32x4 w0 = *(const f32x4*)wp, w1 = *(const f32x4*)(wp+4);
      acc[0] += i0[0]*w0[0]; acc[1] += i0[1]*w0[1]; acc[2] += i0[2]*w0[2]; acc[3] += i0[3]*w0[3];
      acc[4] += i1[0]*w1[0]; acc[5] += i1[1]*w1[1]; acc[6] += i1[2]*w1[2]; acc[7] += i1[3]*w1[3];
    }
  }
  f32x4 c0 = *(const f32x4*)xp, c1 = *(const f32x4*)(xp+4);
  union { bf16x8 v; u16 s[8]; } ov;
  ov.s[0]=f2b(c0[0]+acc[0]); ov.s[1]=f2b(c0[1]+acc[1]); ov.s[2]=f2b(c0[2]+acc[2]); ov.s[3]=f2b(c0[3]+acc[3]);
  ov.s[4]=f2b(c1[0]+acc[4]); ov.s[5]=f2b(c1[1]+acc[5]); ov.s[6]=f2b(c1[2]+acc[6]); ov.s[7]=f2b(c1[3]+acc[7]);
  *(bf16x8*)(x1 + (size_t)row*Cc + ch0) = ov.v;
}

// ---------------- LayerNorm -> bf16.  INF32=0: bf16 input, 1: fp32 input ----------------
template<int INF32>
__global__ __launch_bounds__(256) void ln_kernel(const u16* __restrict__ xb, const float* __restrict__ xf,
                                                 const float* __restrict__ g, const float* __restrict__ b,
                                                 u16* __restrict__ out){
  int row = blockIdx.x*4 + (threadIdx.x>>6);
  int lane = threadIdx.x & 63;
  float v0, v1, v2;
  if (INF32){
    const float* xr = xf + (size_t)row*Cc;
    v0 = xr[lane]; v1 = xr[lane+64]; v2 = xr[lane+128];
  } else {
    const u16* xr = xb + (size_t)row*Cc;
    v0 = b2f(xr[lane]); v1 = b2f(xr[lane+64]); v2 = b2f(xr[lane+128]);
  }
  float s = v0+v1+v2;
  float q = v0*v0 + v1*v1 + v2*v2;
  #pragma unroll
  for (int off=32; off; off>>=1){ s += __shfl_xor(s, off); q += __shfl_xor(q, off); }
  float mu = s*(1.f/Cc);
  float var = q*(1.f/Cc) - mu*mu;
  float rs = rsqrtf(var + 1e-5f);
  u16* orow = out + (size_t)row*Cc;
  orow[lane]     = f2b((v0-mu)*rs*g[lane]     + b[lane]);
  orow[lane+64]  = f2b((v1-mu)*rs*g[lane+64]  + b[lane+64]);
  orow[lane+128] = f2b((v2-mu)*rs*g[lane+128] + b[lane+128]);
}

// ---------------- LDS-staged GEMM: out = epilogue(A[M,KT] @ W[N,KT]^T + bias) ----------------
// Block: BLKM rows x 192 cols, 4 waves (2 row x 2 col), wave = BLKM/2 x 96.
// A staged per-192-K-chunk in LDS (padded stride 200 u16); B reg-double-buffered from L2.
// MODE 0: qkv (col<384 -> qk bf16, col>=384 -> vdst per-head) | 1: fp32 = v + b2f(residb)
// MODE 2: bf16 = gelu(v) width HIDc                           | 3: fp32 = v + residf
template<int MODE, int BLKM, int KT>
__global__ __launch_bounds__(256) void gemm_kernel(
    const u16* __restrict__ A, const u16* __restrict__ Wt,
    const float* __restrict__ bias,
    float* __restrict__ outf, u16* __restrict__ outb,
    u16* __restrict__ vdst, const u16* __restrict__ residb, const float* __restrict__ residf)
{
  constexpr int WROWS = BLKM/2;
  constexpr int NF = WROWS/16;
  constexpr int NCH = KT/192;
  constexpr int NG = BLKM*192/(256*8);
  __shared__ u16 As[BLKM*200];
  int tid = threadIdx.x;
  int wid = tid>>6, lane = tid&63;
  int wr = wid>>1, wc = wid&1;
  int m0 = blockIdx.x*BLKM;
  int n0 = blockIdx.y*192 + wc*96;
  int ar = lane&15, kg = lane>>4;          // kg in 0..3 (8 u16 each)
  f32x4 acc[NF][6];
  #pragma unroll
  for (int f=0;f<NF;f++)
    #pragma unroll
    for (int c=0;c<6;c++){ f32x4 z = {0.f,0.f,0.f,0.f}; acc[f][c] = z; }
  bf16x8 bcur[6], bnxt[6];
  #pragma unroll
  for (int c=0;c<6;c++) bcur[c] = *(const bf16x8*)(Wt + (size_t)(n0 + c*16 + ar)*KT + kg*8);
  #pragma unroll
  for (int ch=0; ch<NCH; ch++){
    if (ch>0) __syncthreads();
    #pragma unroll
    for (int j=0;j<NG;j++){
      int g = j*256 + tid;
      int grow = g/24, gcol = (g - grow*24)*8;
      bf16x8 v = *(const bf16x8*)(A + (size_t)(m0+grow)*KT + ch*192 + gcol);
      *(bf16x8*)(As + grow*200 + gcol) = v;
    }
    __syncthreads();
    #pragma unroll
    for (int kc=0;kc<6;kc++){
      int s = ch*6 + kc;
      if (s+1 < NCH*6){
        int koff = ((s+1)/6)*192 + ((s+1)%6)*32 + kg*8;
        #pragma unroll
        for (int c=0;c<6;c++) bnxt[c] = *(const bf16x8*)(Wt + (size_t)(n0 + c*16 + ar)*KT + koff);
      }
      bf16x8 af[NF];
      #pragma unroll
      for (int f=0;f<NF;f++)
        af[f] = *(const bf16x8*)(As + (wr*WROWS + f*16 + ar)*200 + kc*32 + kg*8);
      #pragma unroll
      for (int f=0;f<NF;f++)
        #pragma unroll
        for (int c=0;c<6;c++)
          acc[f][c] = __builtin_amdgcn_mfma_f32_16x16x32_bf16(af[f], bcur[c], acc[f][c], 0,0,0);
      #pragma unroll
      for (int c=0;c<6;c++) bcur[c] = bnxt[c];
    }
  }
  int rb = kg*4;
  #pragma unroll
  for (int f=0;f<NF;f++){
    #pragma unroll
    for (int c=0;c<6;c++){
      int col = n0 + c*16 + ar;
      float bv = bias[col];
      #pragma unroll
      for (int j=0;j<4;j++){
        int row = m0 + wr*WROWS + f*16 + rb + j;
        float v = acc[f][c][j] + bv;
        if (MODE==0){
          if (col < 384) outb[(size_t)row*384 + col] = f2b(v);
          else {
            int bb = row/Lc; int l = row - bb*Lc;
            int nh = (col-384)>>5; int d = col&31;
            vdst[(((size_t)(bb*NHc+nh))*Lc + l)*DHc + d] = f2b(v);
          }
        } else if (MODE==1){
          outf[(size_t)row*Cc + col] = v + b2f(residb[(size_t)row*Cc + col]);
        } else if (MODE==2){
          float gv = 0.5f*v*(1.f + erff(v*0.70710678118654752f));
          outb[(size_t)row*HIDc + col] = f2b(gv);
        } else {
          outf[(size_t)row*Cc + col] = v + residf[(size_t)row*Cc + col];
        }
      }
    }
  }
}

// ---------------- rope + head reorder, 8 pairs/thread vectorized ----------------
__global__ __launch_bounds__(256) void rope_kernel(const u16* __restrict__ qk, const float* __restrict__ ct,
                                                   const float* __restrict__ st, u16* __restrict__ q_s, u16* __restrict__ k_s){
  int gid = blockIdx.x*256 + threadIdx.x;   // < ROWS*24
  int sub = gid % 24; int row = gid / 24;
  int bb = row / Lc; int l = row - bb*Lc;
  bool isq = sub < 12; int pg = isq ? sub : sub-12;
  int p0 = pg*8;
  int cbase = (isq ? 0 : 192) + 2*p0;
  const u16* qr = qk + (size_t)row*384 + cbase;
  bf16x8 in0 = *(const bf16x8*)qr;
  bf16x8 in1 = *(const bf16x8*)(qr + 8);
  const float* cp = ct + l*96 + p0;
  const float* sp = st + l*96 + p0;
  f32x4 c0 = *(const f32x4*)cp, c1 = *(const f32x4*)(cp+4);
  f32x4 s0 = *(const f32x4*)sp, s1 = *(const f32x4*)(sp+4);
  float cs[8] = {c0[0],c0[1],c0[2],c0[3],c1[0],c1[1],c1[2],c1[3]};
  float sn[8] = {s0[0],s0[1],s0[2],s0[3],s1[0],s1[1],s1[2],s1[3]};
  float sc = isq ? 0.1767766952966369f : 1.0f;
  union { bf16x8 v; u16 s[8]; } o0, o1;
  #pragma unroll
  for (int j=0;j<4;j++){
    float re = b2f((u16)in0[2*j]), im = b2f((u16)in0[2*j+1]);
    o0.s[2*j]   = f2b((cs[j]*re - sn[j]*im)*sc);
    o0.s[2*j+1] = f2b((sn[j]*re + cs[j]*im)*sc);
  }
  #pragma unroll
  for (int j=0;j<4;j++){
    float re = b2f((u16)in1[2*j]), im = b2f((u16)in1[2*j+1]);
    o1.s[2*j]   = f2b((cs[4+j]*re - sn[4+j]*im)*sc);
    o1.s[2*j+1] = f2b((sn[4+j]*re + cs[4+j]*im)*sc);
  }
  int nh = pg>>1, d0 = (pg&1)*16;
  u16* dst = (isq ? q_s : k_s) + (((size_t)(bb*NHc+nh))*Lc + l)*DHc + d0;
  *(bf16x8*)dst = o0.v;
  *(bf16x8*)(dst+8) = o1.v;
}

// ---------------- phase A: per (head,chunk) solve -> U, -R, A'=-K^T R (frags), B=K^T U ----------------
__global__ __launch_bounds__(64) void ttta_kernel(const u16* __restrict__ k_s, const u16* __restrict__ v_s,
                                                  u16* __restrict__ u_s, u16* __restrict__ rn_s,
                                                  u16* __restrict__ af_s, u16* __restrict__ bc_s){
  __shared__ float Gl[1024];
  __shared__ u16 LK[32*40];
  __shared__ float LU[32*33];
  __shared__ float LR[32*33];
  int pair = blockIdx.x;
  int head = pair / NCHUNK;
  int l0 = (pair - head*NCHUNK) * Sc;
  int lane = threadIdx.x; int rr = lane&31; int hi = lane>>5; int ks = hi*8;
  const u16* kb = k_s + ((size_t)head*Lc + l0)*DHc;
  bf16x8 a0 = *(const bf16x8*)(kb + rr*32 + ks);
  bf16x8 a1 = *(const bf16x8*)(kb + rr*32 + 16 + ks);
  *(bf16x8*)(LK + rr*40 + ks) = a0;
  *(bf16x8*)(LK + rr*40 + 16 + ks) = a1;
  f32x16 g = zero16();
  g = __builtin_amdgcn_mfma_f32_32x32x16_bf16(a0, a0, g, 0,0,0);
  g = __builtin_amdgcn_mfma_f32_32x32x16_bf16(a1, a1, g, 0,0,0);
  #pragma unroll
  for (int reg=0;reg<16;reg++){
    int i = (reg&3) + 8*(reg>>2) + 4*hi;
    Gl[i*32 + rr] = ETAc * g[reg];
  }
  __syncthreads();
  float X[32];
  if (lane < 32){
    #pragma unroll
    for (int i=0;i<32;i++) X[i] = ETAc * b2f(v_s[((size_t)head*Lc + l0 + i)*DHc + lane]);
  } else {
    int m = lane-32;
    #pragma unroll
    for (int i=0;i<32;i++) X[i] = ETAc * b2f(kb[i*32 + m]);
  }
  #pragma unroll
  for (int i=1;i<32;i++){
    float a = X[i];
    #pragma unroll
    for (int j=0;j<i;j++) a -= Gl[i*32+j]*X[j];
    X[i] = a;
  }
  if (lane < 32){
    u16* dst = u_s + (size_t)pair*1024 + lane;
    #pragma unroll
    for (int i=0;i<32;i++) dst[i*32] = f2b(X[i]);
    #pragma unroll
    for (int i=0;i<32;i++) LU[lane*33 + i] = X[i];
  } else {
    u16* dst = rn_s + (size_t)pair*1024 + (lane&31);
    #pragma unroll
    for (int i=0;i<32;i++) dst[i*32] = f2b(-X[i]);
    #pragma unroll
    for (int i=0;i<32;i++) LR[(lane&31)*33 + i] = X[i];
  }
  __syncthreads();
  union { bf16x8 v; u16 s[8]; } kc1, kc2, uc1, uc2, rc1, rc2;
  #pragma unroll
  for (int s=0;s<8;s++){
    kc1.s[s] = LK[(ks+s)*40 + rr];
    kc2.s[s] = LK[(16+ks+s)*40 + rr];
    uc1.s[s] = f2b(LU[rr*33 + ks+s]);
    uc2.s[s] = f2b(LU[rr*33 + 16+ks+s]);
    rc1.s[s] = f2b(LR[rr*33 + ks+s]);
    rc2.s[s] = f2b(LR[rr*33 + 16+ks+s]);
  }
  f32x16 bacc = zero16();
  bacc = __builtin_amdgcn_mfma_f32_32x32x16_bf16(kc1.v, uc1.v, bacc, 0,0,0);
  bacc = __builtin_amdgcn_mfma_f32_32x32x16_bf16(kc2.v, uc2.v, bacc, 0,0,0);
  union { bf16x8 v; u16 s[8]; } bo1, bo2;
  #pragma unroll
  for (int r=0;r<8;r++){ bo1.s[r] = f2b(bacc[r]); bo2.s[r] = f2b(bacc[8+r]); }
  *(bf16x8*)(bc_s + (size_t)pair*1024 + lane*16) = bo1.v;
  *(bf16x8*)(bc_s + (size_t)pair*1024 + lane*16 + 8) = bo2.v;
  f32x16 aacc = zero16();
  aacc = __builtin_amdgcn_mfma_f32_32x32x16_bf16(rc1.v, kc1.v, aacc, 0,0,0);
  aacc = __builtin_amdgcn_mfma_f32_32x32x16_bf16(rc2.v, kc2.v, aacc, 0,0,0);
  f32x16 an;
  #pragma unroll
  for (int r=0;r<16;r++) an[r] = -aacc[r];
  bf16x8 f1, f2;
  make_bfrags(an, hi, f1, f2);
  *(bf16x8*)(af_s + (size_t)pair*1024 + lane*16) = f1;
  *(bf16x8*)(af_s + (size_t)pair*1024 + lane*16 + 8) = f2;
}

// ---------------- phase B: MFMA affine scan  T_{c+1} = T_c + A'_c T_c + B_c ----------------
__global__ __launch_bounds__(64) void tttb_kernel(const u16* __restrict__ af_s, const u16* __restrict__ bc_s,
                                                  const float* __restrict__ W0, u16* __restrict__ w_snap){
  int head = blockIdx.x; int nh = head % NHc;
  int lane = threadIdx.x; int rr = lane&31; int hi = lane>>5;
  f32x16 T;
  const float* w0r = W0 + nh*1024 + rr*32 + 4*hi;
  #pragma unroll
  for (int q=0;q<4;q++){
    f32x4 v = *(const f32x4*)(w0r + 8*q);
    T[4*q+0]=v[0]; T[4*q+1]=v[1]; T[4*q+2]=v[2]; T[4*q+3]=v[3];
  }
  size_t hb = (size_t)head*NCHUNK;
  const bf16x8* afp = (const bf16x8*)(af_s + hb*1024);
  const bf16x8* bcp = (const bf16x8*)(bc_s + hb*1024);
  bf16x8 A1 = afp[lane*2], A2 = afp[lane*2+1];
  bf16x8 Bv1 = bcp[lane*2], Bv2 = bcp[lane*2+1];
  bf16x8 b1, b2;
  make_bfrags(T, hi, b1, b2);
  for (int c=0;c<NCHUNK;c++){
    bf16x8 nA1=A1, nA2=A2, nB1=Bv1, nB2=Bv2;
    if (c+1 < NCHUNK){
      int base = (c+1)*128 + lane*2;
      nA1 = afp[base]; nA2 = afp[base+1];
      nB1 = bcp[base]; nB2 = bcp[base+1];
    }
    u16* wrow = w_snap + (hb + c)*1024 + rr*32;
    *(bf16x8*)(wrow + hi*8) = b1;
    *(bf16x8*)(wrow + 16 + hi*8) = b2;
    f32x16 acc;
    #pragma unroll
    for (int r=0;r<8;r++){ acc[r] = T[r] + b2f((u16)Bv1[r]); acc[8+r] = T[8+r] + b2f((u16)Bv2[r]); }
    acc = __builtin_amdgcn_mfma_f32_32x32x16_bf16(A1, b1, acc, 0,0,0);
    acc = __builtin_amdgcn_mfma_f32_32x32x16_bf16(A2, b2, acc, 0,0,0);
    T = acc;
    make_bfrags(T, hi, b1, b2);
    A1=nA1; A2=nA2; Bv1=nB1; Bv2=nB2;
  }
}

// ---------------- phase C: O = Q*T0 + tril(Q K^T)*(U - R*T0) ----------------
__global__ __launch_bounds__(64) void tttc_kernel(const u16* __restrict__ q_s, const u16* __restrict__ k_s,
                                                  const u16* __restrict__ w_snap, const u16* __restrict__ u_s,
                                                  const u16* __restrict__ rn_s, u16* __restrict__ o_bf){
  __shared__ __align__(16) u16 Pl[32*40];
  int pair = blockIdx.x;
  int head = pair / NCHUNK;
  int ch = pair - head*NCHUNK;
  int l0 = ch*Sc;
  int lane = threadIdx.x; int rr = lane&31; int hi = lane>>5; int ks = hi*8;
  const u16* qb = q_s + ((size_t)head*Lc + l0)*DHc;
  const u16* kb = k_s + ((size_t)head*Lc + l0)*DHc;
  bf16x8 q0 = *(const bf16x8*)(qb + rr*32 + ks);
  bf16x8 q1 = *(const bf16x8*)(qb + rr*32 + 16 + ks);
  bf16x8 k0 = *(const bf16x8*)(kb + rr*32 + ks);
  bf16x8 k1 = *(const bf16x8*)(kb + rr*32 + 16 + ks);
  f32x16 p = zero16();
  p = __builtin_amdgcn_mfma_f32_32x32x16_bf16(q0, k0, p, 0,0,0);
  p = __builtin_amdgcn_mfma_f32_32x32x16_bf16(q1, k1, p, 0,0,0);
  #pragma unroll
  for (int reg=0;reg<16;reg++){
    int i = (reg&3)+8*(reg>>2)+4*hi;
    Pl[i*40+rr] = (rr<=i) ? f2b(p[reg]) : (u16)0;
  }
  const u16* wsb = w_snap + (size_t)pair*1024;
  bf16x8 tb0 = *(const bf16x8*)(wsb + rr*32 + ks);
  bf16x8 tb1 = *(const bf16x8*)(wsb + rr*32 + 16 + ks);
  const u16* ub = u_s + (size_t)pair*1024;
  f32x16 wr;
  #pragma unroll
  for (int r=0;r<16;r++){
    int i = (r&3)+8*(r>>2)+4*hi;
    wr[r] = b2f(ub[i*32 + rr]);
  }
  const u16* rb = rn_s + (size_t)pair*1024;
  bf16x8 rn0 = *(const bf16x8*)(rb + rr*32 + ks);
  bf16x8 rn1 = *(const bf16x8*)(rb + rr*32 + 16 + ks);
  wr = __builtin_amdgcn_mfma_f32_32x32x16_bf16(rn0, tb0, wr, 0,0,0);
  wr = __builtin_amdgcn_mfma_f32_32x32x16_bf16(rn1, tb1, wr, 0,0,0);
  bf16x8 wb0, wb1;
  make_bfrags(wr, hi, wb0, wb1);
  __syncthreads();
  f32x16 o = zero16();
  o = __builtin_amdgcn_mfma_f32_32x32x16_bf16(q0, tb0, o, 0,0,0);
  o = __builtin_amdgcn_mfma_f32_32x32x16_bf16(q1, tb1, o, 0,0,0);
  bf16x8 pa0 = *(const bf16x8*)(Pl + rr*40 + ks);
  bf16x8 pa1 = *(const bf16x8*)(Pl + rr*40 + 16 + ks);
  o = __builtin_amdgcn_mfma_f32_32x32x16_bf16(pa0, wb0, o, 0,0,0);
  o = __builtin_amdgcn_mfma_f32_32x32x16_bf16(pa1, wb1, o, 0,0,0);
  int bb = head/NHc, nh = head - bb*NHc;
  #pragma unroll
  for (int reg=0;reg<16;reg++){
    int i = (reg&3)+8*(reg>>2)+4*hi;
    o_bf[((size_t)(bb*Lc + l0 + i))*Cc + nh*32 + rr] = f2b(o[reg]);
  }
}

// ---------------- MLP depthwise conv (HID=768) + gelu, 8 channels/thread ----------------
__global__ __launch_bounds__(256) void dwc_kernel(const u16* __restrict__ h1, const float* __restrict__ wt9,
                                                  const float* __restrict__ bs, u16* __restrict__ h2, int row0){
  int gid = blockIdx.x*256 + threadIdx.x;   // < GR2*96
  int cg = gid % 96; int lrow = gid / 96; int ch0 = cg*8;
  int row = row0 + lrow;
  int l = row % Lc; int h = l/Wcc, w = l - h*Wcc;
  const u16* hp = h1 + (size_t)lrow*HIDc + ch0;
  float acc[8];
  { f32x4 b0 = *(const f32x4*)(bs+ch0), b1v = *(const f32x4*)(bs+ch0+4);
    acc[0]=b0[0];acc[1]=b0[1];acc[2]=b0[2];acc[3]=b0[3];
    acc[4]=b1v[0];acc[5]=b1v[1];acc[6]=b1v[2];acc[7]=b1v[3]; }
  #pragma unroll
  for (int kh=0;kh<3;kh++){
    int hh = h+kh-1; if (hh<0 || hh>=Hc) continue;
    #pragma unroll
    for (int kw=0;kw<3;kw++){
      int ww = w+kw-1; if (ww<0 || ww>=Wcc) continue;
      bf16x8 iv = *(const bf16x8*)(hp + ((kh-1)*Wcc + (kw-1))*HIDc);
      const float* wp = wt9 + (kh*3+kw)*HIDc + ch0;
      f32x4 w0 = *(const f32x4*)wp, w1 = *(const f32x4*)(wp+4);
      acc[0] += b2f((u16)iv[0])*w0[0]; acc[1] += b2f((u16)iv[1])*w0[1];
      acc[2] += b2f((u16)iv[2])*w0[2]; acc[3] += b2f((u16)iv[3])*w0[3];
      acc[4] += b2f((u16)iv[4])*w1[0]; acc[5] += b2f((u16)iv[5])*w1[1];
      acc[6] += b2f((u16)iv[6])*w1[2]; acc[7] += b2f((u16)iv[7])*w1[3];
    }
  }
  bf16x8 cv = *(const bf16x8*)hp;
  union { bf16x8 v; u16 s[8]; } ov;
  #pragma unroll
  for (int j=0;j<8;j++){
    float v = b2f((u16)cv[j]) + acc[j];
    ov.s[j] = f2b(0.5f*v*(1.f + erff(v*0.70710678118654752f)));
  }
  *(bf16x8*)(h2 + (size_t)lrow*HIDc + ch0) = ov.v;
}

// ---------------- launch ----------------
extern "C" void kernel_launch(void* const* d_in, const int* in_sizes, int n_in,
                              void* d_out, int out_size, void* d_ws, size_t ws_size,
                              hipStream_t stream){
  const float* x     = (const float*)d_in[0];
  const float* cpe_w = (const float*)d_in[1];
  const float* cpe_b = (const float*)d_in[2];
  const float* n1_g  = (const float*)d_in[3];
  const float* n1_b  = (const float*)d_in[4];
  const float* qkv_w = (const float*)d_in[5];
  const float* qkv_b = (const float*)d_in[6];
  const float* W0    = (const float*)d_in[7];
  const float* proj_w= (const float*)d_in[8];
  const float* proj_b= (const float*)d_in[9];
  const float* n2_g  = (const float*)d_in[10];
  const float* n2_b  = (const float*)d_in[11];
  const float* fc1_w = (const float*)d_in[12];
  const float* fc1_b = (const float*)d_in[13];
  const float* dwc_w = (const float*)d_in[14];
  const float* dwc_b = (const float*)d_in[15];
  const float* fc2_w = (const float*)d_in[16];
  const float* fc2_b = (const float*)d_in[17];

  char* ws = (char*)d_ws;
  size_t off = 0;
  auto alloc = [&](size_t bytes)->char*{
    char* p = ws + off;
    off += (bytes + 255) & ~(size_t)255;
    return p;
  };
  u16* wbqkv = (u16*)alloc((size_t)576*192*2);
  u16* wbproj= (u16*)alloc((size_t)192*192*2);
  u16* wbfc1 = (u16*)alloc((size_t)768*192*2);
  u16* wbfc2 = (u16*)alloc((size_t)192*768*2);
  float* dwt9 = (float*)alloc((size_t)9*HIDc*4);
  float* cwt9 = (float*)alloc((size_t)9*Cc*4);
  float* ctab = (float*)alloc((size_t)Lc*96*4);
  float* stab = (float*)alloc((size_t)Lc*96*4);
  u16* regA = (u16*)alloc((size_t)ROWS*Cc*2);       // x1
  u16* regB = (u16*)alloc((size_t)ROWS*Cc*2);       // xn -> qs -> xn2
  u16* regD = (u16*)alloc((size_t)NHEAD*Lc*DHc*2);  // vs -> obf -> h1[0:half]
  u16* regE = (u16*)alloc((size_t)NHEAD*Lc*DHc*2);  // ksb -> h1[half:]
  u16* rn_s = (u16*)alloc((size_t)NPAIR*1024*2);    // -R -> h2[0:half]
  u16* af_s = (u16*)alloc((size_t)NPAIR*1024*2);    // A' frags -> h2[half:]
  u16* wsn  = (u16*)alloc((size_t)NPAIR*1024*2);    // T0 snapshots
  // d_out: qk -> [us | bc] -> x2/final
  u16* qk = (u16*)d_out;
  u16* us = (u16*)d_out;
  u16* bc = us + (size_t)NPAIR*1024;
  float* x2 = (float*)d_out;

  u16* x1 = regA;
  u16* xn = regB;
  u16* qs = regB;
  u16* xn2 = regB;
  u16* vs = regD;
  u16* obf = regD;
  u16* ksb = regE;
  u16* h1 = regD;   // spans regD+regE = GR2*768*2 bytes (both dead by MLP)
  u16* h2 = rn_s;   // spans rn_s+af_s = GR2*768*2 bytes (both dead by MLP)

  cast_bf16_kernel<<<(576*192+255)/256,256,0,stream>>>(qkv_w, wbqkv, 576*192);
  cast_bf16_kernel<<<(192*192+255)/256,256,0,stream>>>(proj_w, wbproj, 192*192);
  cast_bf16_kernel<<<(768*192+255)/256,256,0,stream>>>(fc1_w, wbfc1, 768*192);
  cast_bf16_kernel<<<(192*768+255)/256,256,0,stream>>>(fc2_w, wbfc2, 192*768);
  dwt_kernel<<<(768*9+255)/256,256,0,stream>>>(dwc_w, dwt9, HIDc);
  dwt_kernel<<<(192*9+255)/256,256,0,stream>>>(cpe_w, cwt9, Cc);
  rope_tab_kernel<<<(Lc*96)/256,256,0,stream>>>(ctab, stab);

  cpe_kernel<<<(ROWS*24)/256,256,0,stream>>>(x, cwt9, cpe_b, x1);
  ln_kernel<0><<<ROWS/4,256,0,stream>>>(x1, nullptr, n1_g, n1_b, xn);
  { dim3 g(ROWS/128, 3); gemm_kernel<0,128,192><<<g,256,0,stream>>>(xn, wbqkv, qkv_b, nullptr, qk, vs, nullptr, nullptr); }
  rope_kernel<<<(ROWS*24)/256,256,0,stream>>>(qk, ctab, stab, qs, ksb);
  ttta_kernel<<<NPAIR,64,0,stream>>>(ksb, vs, us, rn_s, af_s, bc);
  tttb_kernel<<<NHEAD,64,0,stream>>>(af_s, bc, W0, wsn);
  tttc_kernel<<<NPAIR,64,0,stream>>>(qs, ksb, wsn, us, rn_s, obf);
  { dim3 g(ROWS/128, 1); gemm_kernel<1,128,192><<<g,256,0,stream>>>(obf, wbproj, proj_b, x2, nullptr, nullptr, x1, nullptr); }
  ln_kernel<1><<<ROWS/4,256,0,stream>>>(nullptr, x2, n2_g, n2_b, xn2);
  for (int g4=0; g4<2; g4++){
    const u16* a_in = xn2 + (size_t)g4*GR2*Cc;
    float* xo = x2 + (size_t)g4*GR2*Cc;
    { dim3 g(GR2/128, 4); gemm_kernel<2,128,192><<<g,256,0,stream>>>(a_in, wbfc1, fc1_b, nullptr, h1, nullptr, nullptr, nullptr); }
    dwc_kernel<<<(GR2*96)/256,256,0,stream>>>(h1, dwt9, dwc_b, h2, g4*GR2);
    { dim3 g(GR2/64, 1); gemm_kernel<3,64,768><<<g,256,0,stream>>>(h2, wbfc2, fc2_b, xo, nullptr, nullptr, nullptr, xo); }
  }
}

// Round 7
// 526.215 us; speedup vs baseline: 1.8347x; 1.0520x over previous
//
#include <hip/hip_runtime.h>
#include <hip/hip_bf16.h>

#define Bc 16
#define Hc 56
#define Wcc 56
#define Cc 192
#define NHc 6
#define Lc 3136
#define DHc 32
#define HIDc 768
#define NHEAD 96          // B*NH
#define Sc 32             // chunk length
#define NCHUNK 98         // chunks per head (98*32 = 3136)
#define NPAIR (NHEAD*NCHUNK)
#define ROWS (Bc*Lc)      // 50176
#define GR2 (ROWS/2)      // 25088 rows per MLP group (8 images)
#define ETAc (1.0f/32.0f)

typedef unsigned short u16;
typedef unsigned int u32;
typedef __attribute__((ext_vector_type(8))) short bf16x8;
typedef __attribute__((ext_vector_type(4))) float f32x4;
typedef __attribute__((ext_vector_type(16))) float f32x16;

__device__ __forceinline__ float b2f(u16 v){ u32 u = ((u32)v)<<16; float f; __builtin_memcpy(&f,&u,4); return f; }
__device__ __forceinline__ u16 f2b(float f){ u32 u; __builtin_memcpy(&u,&f,4); u32 r = u + 0x7FFFu + ((u>>16)&1u); return (u16)(r>>16); }
__device__ __forceinline__ f32x16 zero16(){ f32x16 z = {0,0,0,0,0,0,0,0,0,0,0,0,0,0,0,0}; return z; }

// Build b-operand (and a-operand; same layout) bf16 fragments from an f32 accumulator.
__device__ __forceinline__ void make_bfrags(const f32x16& t, int hi, bf16x8& b1, bf16x8& b2){
  u32 P[8], S[8];
  #pragma unroll
  for (int q=0;q<4;q++){
    #pragma unroll
    for (int j=0;j<2;j++){
      u32 r; float lo = t[4*q+2*j], hv = t[4*q+2*j+1];
      asm("v_cvt_pk_bf16_f32 %0, %1, %2" : "=v"(r) : "v"(lo), "v"(hv));
      P[2*q+j] = r;
    }
  }
  #pragma unroll
  for (int i=0;i<8;i++) S[i] = (u32)__shfl_xor((int)P[i], 32);
  union { u32 u[4]; bf16x8 v; } f1, f2;
  if (hi==0){ f1.u[0]=P[0]; f1.u[1]=P[1]; f1.u[2]=S[0]; f1.u[3]=S[1];
              f2.u[0]=P[4]; f2.u[1]=P[5]; f2.u[2]=S[4]; f2.u[3]=S[5]; }
  else      { f1.u[0]=S[2]; f1.u[1]=S[3]; f1.u[2]=P[2]; f1.u[3]=P[3];
              f2.u[0]=S[6]; f2.u[1]=S[7]; f2.u[2]=P[6]; f2.u[3]=P[7]; }
  b1 = f1.v; b2 = f2.v;
}

// ---------------- weight cast ----------------
__global__ __launch_bounds__(256) void cast_bf16_kernel(const float* __restrict__ src, u16* __restrict__ dst, int n){
  int i = blockIdx.x*256 + threadIdx.x;
  if (i < n) dst[i] = f2b(src[i]);
}

// ---------------- dw weight transpose: (CH,9) -> (9,CH) ----------------
__global__ __launch_bounds__(256) void dwt_kernel(const float* __restrict__ w, float* __restrict__ wt, int CH){
  int i = blockIdx.x*256 + threadIdx.x;
  if (i < CH*9){ int ch = i/9, t = i - ch*9; wt[t*CH + ch] = w[i]; }
}

// ---------------- rope tables ----------------
__global__ __launch_bounds__(256) void rope_tab_kernel(float* __restrict__ ct, float* __restrict__ st){
  int i = blockIdx.x*256 + threadIdx.x;   // < Lc*96
  int l = i/96, p = i - l*96;
  int h = l/Wcc, w = l - h*Wcc;
  int kk = (p<48)? p : p-48;
  float th = powf(10000.f, -(float)kk/48.f);
  float ang = (float)((p<48)? h : w) * th;
  ct[i] = cosf(ang);
  st[i] = sinf(ang);
}

// ---------------- CPE depthwise conv (C=192), 8 ch/thread, vectorized ----------------
__global__ __launch_bounds__(256) void cpe_kernel(const float* __restrict__ x, const float* __restrict__ cwt9,
                                                  const float* __restrict__ bs, u16* __restrict__ x1){
  int gid = blockIdx.x*256 + threadIdx.x;   // < ROWS*24
  int cg = gid % 24; int row = gid / 24; int ch0 = cg*8;
  int l = row % Lc; int h = l/Wcc, w = l - h*Wcc;
  const float* xp = x + (size_t)row*Cc + ch0;
  float acc[8];
  { f32x4 b0 = *(const f32x4*)(bs+ch0), b1v = *(const f32x4*)(bs+ch0+4);
    acc[0]=b0[0];acc[1]=b0[1];acc[2]=b0[2];acc[3]=b0[3];
    acc[4]=b1v[0];acc[5]=b1v[1];acc[6]=b1v[2];acc[7]=b1v[3]; }
  #pragma unroll
  for (int kh=0;kh<3;kh++){
    int hh = h+kh-1; if (hh<0 || hh>=Hc) continue;
    #pragma unroll
    for (int kw=0;kw<3;kw++){
      int ww = w+kw-1; if (ww<0 || ww>=Wcc) continue;
      const float* ip = xp + ((kh-1)*Wcc + (kw-1))*Cc;
      f32x4 i0 = *(const f32x4*)ip, i1 = *(const f32x4*)(ip+4);
      const float* wp = cwt9 + (kh*3+kw)*Cc + ch0;
      f32x4 w0 = *(const f32x4*)wp, w1 = *(const f32x4*)(wp+4);
      acc[0] += i0[0]*w0[0]; acc[1] += i0[1]*w0[1]; acc[2] += i0[2]*w0[2]; acc[3] += i0[3]*w0[3];
      acc[4] += i1[0]*w1[0]; acc[5] += i1[1]*w1[1]; acc[6] += i1[2]*w1[2]; acc[7] += i1[3]*w1[3];
    }
  }
  f32x4 c0 = *(const f32x4*)xp, c1 = *(const f32x4*)(xp+4);
  union { bf16x8 v; u16 s[8]; } ov;
  ov.s[0]=f2b(c0[0]+acc[0]); ov.s[1]=f2b(c0[1]+acc[1]); ov.s[2]=f2b(c0[2]+acc[2]); ov.s[3]=f2b(c0[3]+acc[3]);
  ov.s[4]=f2b(c1[0]+acc[4]); ov.s[5]=f2b(c1[1]+acc[5]); ov.s[6]=f2b(c1[2]+acc[6]); ov.s[7]=f2b(c1[3]+acc[7]);
  *(bf16x8*)(x1 + (size_t)row*Cc + ch0) = ov.v;
}

// ---------------- LayerNorm -> bf16.  INF32=0: bf16 input, 1: fp32 input ----------------
template<int INF32>
__global__ __launch_bounds__(256) void ln_kernel(const u16* __restrict__ xb, const float* __restrict__ xf,
                                                 const float* __restrict__ g, const float* __restrict__ b,
                                                 u16* __restrict__ out){
  int row = blockIdx.x*4 + (threadIdx.x>>6);
  int lane = threadIdx.x & 63;
  float v0, v1, v2;
  if (INF32){
    const float* xr = xf + (size_t)row*Cc;
    v0 = xr[lane]; v1 = xr[lane+64]; v2 = xr[lane+128];
  } else {
    const u16* xr = xb + (size_t)row*Cc;
    v0 = b2f(xr[lane]); v1 = b2f(xr[lane+64]); v2 = b2f(xr[lane+128]);
  }
  float s = v0+v1+v2;
  float q = v0*v0 + v1*v1 + v2*v2;
  #pragma unroll
  for (int off=32; off; off>>=1){ s += __shfl_xor(s, off); q += __shfl_xor(q, off); }
  float mu = s*(1.f/Cc);
  float var = q*(1.f/Cc) - mu*mu;
  float rs = rsqrtf(var + 1e-5f);
  u16* orow = out + (size_t)row*Cc;
  orow[lane]     = f2b((v0-mu)*rs*g[lane]     + b[lane]);
  orow[lane+64]  = f2b((v1-mu)*rs*g[lane+64]  + b[lane+64]);
  orow[lane+128] = f2b((v2-mu)*rs*g[lane+128] + b[lane+128]);
}

// ---------------- LDS-staged GEMM, BLKM=64, coalesced LDS-transpose epilogue ----------------
// Block: 64 rows x 192 cols, 4 waves (2 row x 2 col), wave = 32 x 96.
// MODE 0: qkv (col<384 -> qk bf16 row-major, col>=384 -> vdst per-head) | 1: fp32 = v + b2f(residb)
// MODE 2: bf16 = gelu(v), width HIDc                                   | 3: fp32 = v + residf
template<int MODE, int KT>
__global__ __launch_bounds__(256) void gemm_kernel(
    const u16* __restrict__ A, const u16* __restrict__ Wt,
    const float* __restrict__ bias,
    float* __restrict__ outf, u16* __restrict__ outb,
    u16* __restrict__ vdst, const u16* __restrict__ residb, const float* __restrict__ residf)
{
  constexpr int NCH = KT/192;
  __shared__ __align__(16) char smem[64*200*2];   // As[64][200] u16  |  Os32[64][100] f32  |  Osu[64][200] u16
  u16* As = (u16*)smem;
  float* Os32 = (float*)smem;
  u16* Osu = (u16*)smem;
  int tid = threadIdx.x;
  int wid = tid>>6, lane = tid&63;
  int wr = wid>>1, wc = wid&1;
  int m0 = blockIdx.x*64;
  int nblk = blockIdx.y*192;
  int n0 = nblk + wc*96;
  int ar = lane&15, kg = lane>>4;          // kg in 0..3
  f32x4 acc[2][6];
  #pragma unroll
  for (int f=0;f<2;f++)
    #pragma unroll
    for (int c=0;c<6;c++){ f32x4 z = {0.f,0.f,0.f,0.f}; acc[f][c] = z; }
  bf16x8 bcur[6], bnxt[6];
  #pragma unroll
  for (int c=0;c<6;c++) bcur[c] = *(const bf16x8*)(Wt + (size_t)(n0 + c*16 + ar)*KT + kg*8);
  #pragma unroll
  for (int ch=0; ch<NCH; ch++){
    if (ch>0) __syncthreads();
    #pragma unroll
    for (int j=0;j<6;j++){
      int g = j*256 + tid;
      int grow = g/24, gcol = (g - grow*24)*8;
      bf16x8 v = *(const bf16x8*)(A + (size_t)(m0+grow)*KT + ch*192 + gcol);
      *(bf16x8*)(As + grow*200 + gcol) = v;
    }
    __syncthreads();
    #pragma unroll
    for (int kc=0;kc<6;kc++){
      int s = ch*6 + kc;
      if (s+1 < NCH*6){
        int koff = ((s+1)/6)*192 + ((s+1)%6)*32 + kg*8;
        #pragma unroll
        for (int c=0;c<6;c++) bnxt[c] = *(const bf16x8*)(Wt + (size_t)(n0 + c*16 + ar)*KT + koff);
      }
      bf16x8 af[2];
      #pragma unroll
      for (int f=0;f<2;f++)
        af[f] = *(const bf16x8*)(As + (wr*32 + f*16 + ar)*200 + kc*32 + kg*8);
      #pragma unroll
      for (int f=0;f<2;f++)
        #pragma unroll
        for (int c=0;c<6;c++)
          acc[f][c] = __builtin_amdgcn_mfma_f32_16x16x32_bf16(af[f], bcur[c], acc[f][c], 0,0,0);
      #pragma unroll
      for (int c=0;c<6;c++) bcur[c] = bnxt[c];
    }
  }
  __syncthreads();   // all As reads done; smem now reused for output staging
  if (MODE==0 || MODE==2){
    #pragma unroll
    for (int f=0;f<2;f++){
      #pragma unroll
      for (int c=0;c<6;c++){
        float bv = bias[n0 + c*16 + ar];
        #pragma unroll
        for (int j=0;j<4;j++){
          float v = acc[f][c][j] + bv;
          if (MODE==2) v = 0.5f*v*(1.f + erff(v*0.70710678118654752f));
          Osu[(wr*32 + f*16 + kg*4 + j)*200 + wc*96 + c*16 + ar] = f2b(v);
        }
      }
    }
    __syncthreads();
    #pragma unroll
    for (int j=0;j<6;j++){
      int g = j*256 + tid;
      int grow = g/24, gcol = (g - grow*24)*8;
      bf16x8 v = *(const bf16x8*)(Osu + grow*200 + gcol);
      int row = m0 + grow, col = nblk + gcol;
      if (MODE==2){
        *(bf16x8*)(outb + (size_t)row*HIDc + col) = v;
      } else if (col < 384){
        *(bf16x8*)(outb + (size_t)row*384 + col) = v;
      } else {
        int bb = row/Lc; int l = row - bb*Lc;
        int nh = gcol>>5, d = gcol&31;
        *(bf16x8*)(vdst + (((size_t)(bb*NHc+nh))*Lc + l)*DHc + d) = v;
      }
    }
  } else {
    #pragma unroll
    for (int half=0; half<2; half++){
      if (wc==half){
        #pragma unroll
        for (int f=0;f<2;f++){
          #pragma unroll
          for (int c=0;c<6;c++){
            float bv = bias[n0 + c*16 + ar];
            #pragma unroll
            for (int j=0;j<4;j++)
              Os32[(wr*32 + f*16 + kg*4 + j)*100 + c*16 + ar] = acc[f][c][j] + bv;
          }
        }
      }
      __syncthreads();
      #pragma unroll
      for (int j=0;j<6;j++){
        int g = j*256 + tid;
        int grow = g/24, qcol = (g - grow*24)*4;
        f32x4 v = *(const f32x4*)(Os32 + grow*100 + qcol);
        int row = m0 + grow, colg = half*96 + qcol;
        if (MODE==1){
          const u16* rp = residb + (size_t)row*Cc + colg;
          v[0] += b2f(rp[0]); v[1] += b2f(rp[1]); v[2] += b2f(rp[2]); v[3] += b2f(rp[3]);
        } else {
          f32x4 rv = *(const f32x4*)(residf + (size_t)row*Cc + colg);
          v[0] += rv[0]; v[1] += rv[1]; v[2] += rv[2]; v[3] += rv[3];
        }
        *(f32x4*)(outf + (size_t)row*Cc + colg) = v;
      }
      if (half==0) __syncthreads();
    }
  }
}

// ---------------- rope + head reorder, 8 pairs/thread vectorized ----------------
__global__ __launch_bounds__(256) void rope_kernel(const u16* __restrict__ qk, const float* __restrict__ ct,
                                                   const float* __restrict__ st, u16* __restrict__ q_s, u16* __restrict__ k_s){
  int gid = blockIdx.x*256 + threadIdx.x;   // < ROWS*24
  int sub = gid % 24; int row = gid / 24;
  int bb = row / Lc; int l = row - bb*Lc;
  bool isq = sub < 12; int pg = isq ? sub : sub-12;
  int p0 = pg*8;
  int cbase = (isq ? 0 : 192) + 2*p0;
  const u16* qr = qk + (size_t)row*384 + cbase;
  bf16x8 in0 = *(const bf16x8*)qr;
  bf16x8 in1 = *(const bf16x8*)(qr + 8);
  const float* cp = ct + l*96 + p0;
  const float* sp = st + l*96 + p0;
  f32x4 c0 = *(const f32x4*)cp, c1 = *(const f32x4*)(cp+4);
  f32x4 s0 = *(const f32x4*)sp, s1 = *(const f32x4*)(sp+4);
  float cs[8] = {c0[0],c0[1],c0[2],c0[3],c1[0],c1[1],c1[2],c1[3]};
  float sn[8] = {s0[0],s0[1],s0[2],s0[3],s1[0],s1[1],s1[2],s1[3]};
  float sc = isq ? 0.1767766952966369f : 1.0f;
  union { bf16x8 v; u16 s[8]; } o0, o1;
  #pragma unroll
  for (int j=0;j<4;j++){
    float re = b2f((u16)in0[2*j]), im = b2f((u16)in0[2*j+1]);
    o0.s[2*j]   = f2b((cs[j]*re - sn[j]*im)*sc);
    o0.s[2*j+1] = f2b((sn[j]*re + cs[j]*im)*sc);
  }
  #pragma unroll
  for (int j=0;j<4;j++){
    float re = b2f((u16)in1[2*j]), im = b2f((u16)in1[2*j+1]);
    o1.s[2*j]   = f2b((cs[4+j]*re - sn[4+j]*im)*sc);
    o1.s[2*j+1] = f2b((sn[4+j]*re + cs[4+j]*im)*sc);
  }
  int nh = pg>>1, d0 = (pg&1)*16;
  u16* dst = (isq ? q_s : k_s) + (((size_t)(bb*NHc+nh))*Lc + l)*DHc + d0;
  *(bf16x8*)dst = o0.v;
  *(bf16x8*)(dst+8) = o1.v;
}

// ---------------- phase A: per (head,chunk) solve -> U, -R, A'=-K^T R (frags), B=K^T U ----------------
__global__ __launch_bounds__(64) void ttta_kernel(const u16* __restrict__ k_s, const u16* __restrict__ v_s,
                                                  u16* __restrict__ u_s, u16* __restrict__ rn_s,
                                                  u16* __restrict__ af_s, u16* __restrict__ bc_s){
  __shared__ float Gl[1024];
  __shared__ u16 LK[32*40];
  __shared__ float LU[32*33];
  __shared__ float LR[32*33];
  int pair = blockIdx.x;
  int head = pair / NCHUNK;
  int l0 = (pair - head*NCHUNK) * Sc;
  int lane = threadIdx.x; int rr = lane&31; int hi = lane>>5; int ks = hi*8;
  const u16* kb = k_s + ((size_t)head*Lc + l0)*DHc;
  bf16x8 a0 = *(const bf16x8*)(kb + rr*32 + ks);
  bf16x8 a1 = *(const bf16x8*)(kb + rr*32 + 16 + ks);
  *(bf16x8*)(LK + rr*40 + ks) = a0;
  *(bf16x8*)(LK + rr*40 + 16 + ks) = a1;
  f32x16 g = zero16();
  g = __builtin_amdgcn_mfma_f32_32x32x16_bf16(a0, a0, g, 0,0,0);
  g = __builtin_amdgcn_mfma_f32_32x32x16_bf16(a1, a1, g, 0,0,0);
  #pragma unroll
  for (int reg=0;reg<16;reg++){
    int i = (reg&3) + 8*(reg>>2) + 4*hi;
    Gl[i*32 + rr] = ETAc * g[reg];
  }
  __syncthreads();
  float X[32];
  if (lane < 32){
    #pragma unroll
    for (int i=0;i<32;i++) X[i] = ETAc * b2f(v_s[((size_t)head*Lc + l0 + i)*DHc + lane]);
  } else {
    int m = lane-32;
    #pragma unroll
    for (int i=0;i<32;i++) X[i] = ETAc * b2f(kb[i*32 + m]);
  }
  #pragma unroll
  for (int i=1;i<32;i++){
    float a = X[i];
    #pragma unroll
    for (int j=0;j<i;j++) a -= Gl[i*32+j]*X[j];
    X[i] = a;
  }
  if (lane < 32){
    u16* dst = u_s + (size_t)pair*1024 + lane;
    #pragma unroll
    for (int i=0;i<32;i++) dst[i*32] = f2b(X[i]);
    #pragma unroll
    for (int i=0;i<32;i++) LU[lane*33 + i] = X[i];
  } else {
    u16* dst = rn_s + (size_t)pair*1024 + (lane&31);
    #pragma unroll
    for (int i=0;i<32;i++) dst[i*32] = f2b(-X[i]);
    #pragma unroll
    for (int i=0;i<32;i++) LR[(lane&31)*33 + i] = X[i];
  }
  __syncthreads();
  union { bf16x8 v; u16 s[8]; } kc1, kc2, uc1, uc2, rc1, rc2;
  #pragma unroll
  for (int s=0;s<8;s++){
    kc1.s[s] = LK[(ks+s)*40 + rr];
    kc2.s[s] = LK[(16+ks+s)*40 + rr];
    uc1.s[s] = f2b(LU[rr*33 + ks+s]);
    uc2.s[s] = f2b(LU[rr*33 + 16+ks+s]);
    rc1.s[s] = f2b(LR[rr*33 + ks+s]);
    rc2.s[s] = f2b(LR[rr*33 + 16+ks+s]);
  }
  f32x16 bacc = zero16();
  bacc = __builtin_amdgcn_mfma_f32_32x32x16_bf16(kc1.v, uc1.v, bacc, 0,0,0);
  bacc = __builtin_amdgcn_mfma_f32_32x32x16_bf16(kc2.v, uc2.v, bacc, 0,0,0);
  union { bf16x8 v; u16 s[8]; } bo1, bo2;
  #pragma unroll
  for (int r=0;r<8;r++){ bo1.s[r] = f2b(bacc[r]); bo2.s[r] = f2b(bacc[8+r]); }
  *(bf16x8*)(bc_s + (size_t)pair*1024 + lane*16) = bo1.v;
  *(bf16x8*)(bc_s + (size_t)pair*1024 + lane*16 + 8) = bo2.v;
  f32x16 aacc = zero16();
  aacc = __builtin_amdgcn_mfma_f32_32x32x16_bf16(rc1.v, kc1.v, aacc, 0,0,0);
  aacc = __builtin_amdgcn_mfma_f32_32x32x16_bf16(rc2.v, kc2.v, aacc, 0,0,0);
  f32x16 an;
  #pragma unroll
  for (int r=0;r<16;r++) an[r] = -aacc[r];
  bf16x8 f1, f2;
  make_bfrags(an, hi, f1, f2);
  *(bf16x8*)(af_s + (size_t)pair*1024 + lane*16) = f1;
  *(bf16x8*)(af_s + (size_t)pair*1024 + lane*16 + 8) = f2;
}

// ---------------- phase B: MFMA affine scan  T_{c+1} = T_c + A'_c T_c + B_c ----------------
__global__ __launch_bounds__(64) void tttb_kernel(const u16* __restrict__ af_s, const u16* __restrict__ bc_s,
                                                  const float* __restrict__ W0, u16* __restrict__ w_snap){
  int head = blockIdx.x; int nh = head % NHc;
  int lane = threadIdx.x; int rr = lane&31; int hi = lane>>5;
  f32x16 T;
  const float* w0r = W0 + nh*1024 + rr*32 + 4*hi;
  #pragma unroll
  for (int q=0;q<4;q++){
    f32x4 v = *(const f32x4*)(w0r + 8*q);
    T[4*q+0]=v[0]; T[4*q+1]=v[1]; T[4*q+2]=v[2]; T[4*q+3]=v[3];
  }
  size_t hb = (size_t)head*NCHUNK;
  const bf16x8* afp = (const bf16x8*)(af_s + hb*1024);
  const bf16x8* bcp = (const bf16x8*)(bc_s + hb*1024);
  bf16x8 A1 = afp[lane*2], A2 = afp[lane*2+1];
  bf16x8 Bv1 = bcp[lane*2], Bv2 = bcp[lane*2+1];
  bf16x8 b1, b2;
  make_bfrags(T, hi, b1, b2);
  for (int c=0;c<NCHUNK;c++){
    bf16x8 nA1=A1, nA2=A2, nB1=Bv1, nB2=Bv2;
    if (c+1 < NCHUNK){
      int base = (c+1)*128 + lane*2;
      nA1 = afp[base]; nA2 = afp[base+1];
      nB1 = bcp[base]; nB2 = bcp[base+1];
    }
    u16* wrow = w_snap + (hb + c)*1024 + rr*32;
    *(bf16x8*)(wrow + hi*8) = b1;
    *(bf16x8*)(wrow + 16 + hi*8) = b2;
    f32x16 acc;
    #pragma unroll
    for (int r=0;r<8;r++){ acc[r] = T[r] + b2f((u16)Bv1[r]); acc[8+r] = T[8+r] + b2f((u16)Bv2[r]); }
    acc = __builtin_amdgcn_mfma_f32_32x32x16_bf16(A1, b1, acc, 0,0,0);
    acc = __builtin_amdgcn_mfma_f32_32x32x16_bf16(A2, b2, acc, 0,0,0);
    T = acc;
    make_bfrags(T, hi, b1, b2);
    A1=nA1; A2=nA2; Bv1=nB1; Bv2=nB2;
  }
}

// ---------------- phase C: O = Q*T0 + tril(Q K^T)*(U - R*T0) ----------------
__global__ __launch_bounds__(64) void tttc_kernel(const u16* __restrict__ q_s, const u16* __restrict__ k_s,
                                                  const u16* __restrict__ w_snap, const u16* __restrict__ u_s,
                                                  const u16* __restrict__ rn_s, u16* __restrict__ o_bf){
  __shared__ __align__(16) u16 Pl[32*40];
  int pair = blockIdx.x;
  int head = pair / NCHUNK;
  int ch = pair - head*NCHUNK;
  int l0 = ch*Sc;
  int lane = threadIdx.x; int rr = lane&31; int hi = lane>>5; int ks = hi*8;
  const u16* qb = q_s + ((size_t)head*Lc + l0)*DHc;
  const u16* kb = k_s + ((size_t)head*Lc + l0)*DHc;
  bf16x8 q0 = *(const bf16x8*)(qb + rr*32 + ks);
  bf16x8 q1 = *(const bf16x8*)(qb + rr*32 + 16 + ks);
  bf16x8 k0 = *(const bf16x8*)(kb + rr*32 + ks);
  bf16x8 k1 = *(const bf16x8*)(kb + rr*32 + 16 + ks);
  f32x16 p = zero16();
  p = __builtin_amdgcn_mfma_f32_32x32x16_bf16(q0, k0, p, 0,0,0);
  p = __builtin_amdgcn_mfma_f32_32x32x16_bf16(q1, k1, p, 0,0,0);
  #pragma unroll
  for (int reg=0;reg<16;reg++){
    int i = (reg&3)+8*(reg>>2)+4*hi;
    Pl[i*40+rr] = (rr<=i) ? f2b(p[reg]) : (u16)0;
  }
  const u16* wsb = w_snap + (size_t)pair*1024;
  bf16x8 tb0 = *(const bf16x8*)(wsb + rr*32 + ks);
  bf16x8 tb1 = *(const bf16x8*)(wsb + rr*32 + 16 + ks);
  const u16* ub = u_s + (size_t)pair*1024;
  f32x16 wr;
  #pragma unroll
  for (int r=0;r<16;r++){
    int i = (r&3)+8*(r>>2)+4*hi;
    wr[r] = b2f(ub[i*32 + rr]);
  }
  const u16* rb = rn_s + (size_t)pair*1024;
  bf16x8 rn0 = *(const bf16x8*)(rb + rr*32 + ks);
  bf16x8 rn1 = *(const bf16x8*)(rb + rr*32 + 16 + ks);
  wr = __builtin_amdgcn_mfma_f32_32x32x16_bf16(rn0, tb0, wr, 0,0,0);
  wr = __builtin_amdgcn_mfma_f32_32x32x16_bf16(rn1, tb1, wr, 0,0,0);
  bf16x8 wb0, wb1;
  make_bfrags(wr, hi, wb0, wb1);
  __syncthreads();
  f32x16 o = zero16();
  o = __builtin_amdgcn_mfma_f32_32x32x16_bf16(q0, tb0, o, 0,0,0);
  o = __builtin_amdgcn_mfma_f32_32x32x16_bf16(q1, tb1, o, 0,0,0);
  bf16x8 pa0 = *(const bf16x8*)(Pl + rr*40 + ks);
  bf16x8 pa1 = *(const bf16x8*)(Pl + rr*40 + 16 + ks);
  o = __builtin_amdgcn_mfma_f32_32x32x16_bf16(pa0, wb0, o, 0,0,0);
  o = __builtin_amdgcn_mfma_f32_32x32x16_bf16(pa1, wb1, o, 0,0,0);
  int bb = head/NHc, nh = head - bb*NHc;
  #pragma unroll
  for (int reg=0;reg<16;reg++){
    int i = (reg&3)+8*(reg>>2)+4*hi;
    o_bf[((size_t)(bb*Lc + l0 + i))*Cc + nh*32 + rr] = f2b(o[reg]);
  }
}

// ---------------- MLP depthwise conv (HID=768) + gelu, 8 channels/thread ----------------
__global__ __launch_bounds__(256) void dwc_kernel(const u16* __restrict__ h1, const float* __restrict__ wt9,
                                                  const float* __restrict__ bs, u16* __restrict__ h2, int row0){
  int gid = blockIdx.x*256 + threadIdx.x;   // < GR2*96
  int cg = gid % 96; int lrow = gid / 96; int ch0 = cg*8;
  int row = row0 + lrow;
  int l = row % Lc; int h = l/Wcc, w = l - h*Wcc;
  const u16* hp = h1 + (size_t)lrow*HIDc + ch0;
  float acc[8];
  { f32x4 b0 = *(const f32x4*)(bs+ch0), b1v = *(const f32x4*)(bs+ch0+4);
    acc[0]=b0[0];acc[1]=b0[1];acc[2]=b0[2];acc[3]=b0[3];
    acc[4]=b1v[0];acc[5]=b1v[1];acc[6]=b1v[2];acc[7]=b1v[3]; }
  #pragma unroll
  for (int kh=0;kh<3;kh++){
    int hh = h+kh-1; if (hh<0 || hh>=Hc) continue;
    #pragma unroll
    for (int kw=0;kw<3;kw++){
      int ww = w+kw-1; if (ww<0 || ww>=Wcc) continue;
      bf16x8 iv = *(const bf16x8*)(hp + ((kh-1)*Wcc + (kw-1))*HIDc);
      const float* wp = wt9 + (kh*3+kw)*HIDc + ch0;
      f32x4 w0 = *(const f32x4*)wp, w1 = *(const f32x4*)(wp+4);
      acc[0] += b2f((u16)iv[0])*w0[0]; acc[1] += b2f((u16)iv[1])*w0[1];
      acc[2] += b2f((u16)iv[2])*w0[2]; acc[3] += b2f((u16)iv[3])*w0[3];
      acc[4] += b2f((u16)iv[4])*w1[0]; acc[5] += b2f((u16)iv[5])*w1[1];
      acc[6] += b2f((u16)iv[6])*w1[2]; acc[7] += b2f((u16)iv[7])*w1[3];
    }
  }
  bf16x8 cv = *(const bf16x8*)hp;
  union { bf16x8 v; u16 s[8]; } ov;
  #pragma unroll
  for (int j=0;j<8;j++){
    float v = b2f((u16)cv[j]) + acc[j];
    ov.s[j] = f2b(0.5f*v*(1.f + erff(v*0.70710678118654752f)));
  }
  *(bf16x8*)(h2 + (size_t)lrow*HIDc + ch0) = ov.v;
}

// ---------------- launch ----------------
extern "C" void kernel_launch(void* const* d_in, const int* in_sizes, int n_in,
                              void* d_out, int out_size, void* d_ws, size_t ws_size,
                              hipStream_t stream){
  const float* x     = (const float*)d_in[0];
  const float* cpe_w = (const float*)d_in[1];
  const float* cpe_b = (const float*)d_in[2];
  const float* n1_g  = (const float*)d_in[3];
  const float* n1_b  = (const float*)d_in[4];
  const float* qkv_w = (const float*)d_in[5];
  const float* qkv_b = (const float*)d_in[6];
  const float* W0    = (const float*)d_in[7];
  const float* proj_w= (const float*)d_in[8];
  const float* proj_b= (const float*)d_in[9];
  const float* n2_g  = (const float*)d_in[10];
  const float* n2_b  = (const float*)d_in[11];
  const float* fc1_w = (const float*)d_in[12];
  const float* fc1_b = (const float*)d_in[13];
  const float* dwc_w = (const float*)d_in[14];
  const float* dwc_b = (const float*)d_in[15];
  const float* fc2_w = (const float*)d_in[16];
  const float* fc2_b = (const float*)d_in[17];

  char* ws = (char*)d_ws;
  size_t off = 0;
  auto alloc = [&](size_t bytes)->char*{
    char* p = ws + off;
    off += (bytes + 255) & ~(size_t)255;
    return p;
  };
  u16* wbqkv = (u16*)alloc((size_t)576*192*2);
  u16* wbproj= (u16*)alloc((size_t)192*192*2);
  u16* wbfc1 = (u16*)alloc((size_t)768*192*2);
  u16* wbfc2 = (u16*)alloc((size_t)192*768*2);
  float* dwt9 = (float*)alloc((size_t)9*HIDc*4);
  float* cwt9 = (float*)alloc((size_t)9*Cc*4);
  float* ctab = (float*)alloc((size_t)Lc*96*4);
  float* stab = (float*)alloc((size_t)Lc*96*4);
  u16* regA = (u16*)alloc((size_t)ROWS*Cc*2);       // x1
  u16* regB = (u16*)alloc((size_t)ROWS*Cc*2);       // xn -> qs -> xn2
  u16* regD = (u16*)alloc((size_t)NHEAD*Lc*DHc*2);  // vs -> obf -> h1[0:half]
  u16* regE = (u16*)alloc((size_t)NHEAD*Lc*DHc*2);  // ksb -> h1[half:]
  u16* rn_s = (u16*)alloc((size_t)NPAIR*1024*2);    // -R -> h2[0:half]
  u16* af_s = (u16*)alloc((size_t)NPAIR*1024*2);    // A' frags -> h2[half:]
  u16* wsn  = (u16*)alloc((size_t)NPAIR*1024*2);    // T0 snapshots
  // d_out: qk -> [us | bc] -> x2/final
  u16* qk = (u16*)d_out;
  u16* us = (u16*)d_out;
  u16* bc = us + (size_t)NPAIR*1024;
  float* x2 = (float*)d_out;

  u16* x1 = regA;
  u16* xn = regB;
  u16* qs = regB;
  u16* xn2 = regB;
  u16* vs = regD;
  u16* obf = regD;
  u16* ksb = regE;
  u16* h1 = regD;   // spans regD+regE = GR2*768*2 bytes (both dead by MLP)
  u16* h2 = rn_s;   // spans rn_s+af_s = GR2*768*2 bytes (both dead by MLP)

  cast_bf16_kernel<<<(576*192+255)/256,256,0,stream>>>(qkv_w, wbqkv, 576*192);
  cast_bf16_kernel<<<(192*192+255)/256,256,0,stream>>>(proj_w, wbproj, 192*192);
  cast_bf16_kernel<<<(768*192+255)/256,256,0,stream>>>(fc1_w, wbfc1, 768*192);
  cast_bf16_kernel<<<(192*768+255)/256,256,0,stream>>>(fc2_w, wbfc2, 192*768);
  dwt_kernel<<<(768*9+255)/256,256,0,stream>>>(dwc_w, dwt9, HIDc);
  dwt_kernel<<<(192*9+255)/256,256,0,stream>>>(cpe_w, cwt9, Cc);
  rope_tab_kernel<<<(Lc*96)/256,256,0,stream>>>(ctab, stab);

  cpe_kernel<<<(ROWS*24)/256,256,0,stream>>>(x, cwt9, cpe_b, x1);
  ln_kernel<0><<<ROWS/4,256,0,stream>>>(x1, nullptr, n1_g, n1_b, xn);
  { dim3 g(ROWS/64, 3); gemm_kernel<0,192><<<g,256,0,stream>>>(xn, wbqkv, qkv_b, nullptr, qk, vs, nullptr, nullptr); }
  rope_kernel<<<(ROWS*24)/256,256,0,stream>>>(qk, ctab, stab, qs, ksb);
  ttta_kernel<<<NPAIR,64,0,stream>>>(ksb, vs, us, rn_s, af_s, bc);
  tttb_kernel<<<NHEAD,64,0,stream>>>(af_s, bc, W0, wsn);
  tttc_kernel<<<NPAIR,64,0,stream>>>(qs, ksb, wsn, us, rn_s, obf);
  { dim3 g(ROWS/64, 1); gemm_kernel<1,192><<<g,256,0,stream>>>(obf, wbproj, proj_b, x2, nullptr, nullptr, x1, nullptr); }
  ln_kernel<1><<<ROWS/4,256,0,stream>>>(nullptr, x2, n2_g, n2_b, xn2);
  for (int g4=0; g4<2; g4++){
    const u16* a_in = xn2 + (size_t)g4*GR2*Cc;
    float* xo = x2 + (size_t)g4*GR2*Cc;
    { dim3 g(GR2/64, 4); gemm_kernel<2,192><<<g,256,0,stream>>>(a_in, wbfc1, fc1_b, nullptr, h1, nullptr, nullptr, nullptr); }
    dwc_kernel<<<(GR2*96)/256,256,0,stream>>>(h1, dwt9, dwc_b, h2, g4*GR2);
    { dim3 g(GR2/64, 1); gemm_kernel<3,768><<<g,256,0,stream>>>(h2, wbfc2, fc2_b, xo, nullptr, nullptr, nullptr, xo); }
  }
}

// Round 8
// 503.291 us; speedup vs baseline: 1.9183x; 1.0455x over previous
//
#include <hip/hip_runtime.h>
#include <hip/hip_bf16.h>

#define Bc 16
#define Hc 56
#define Wcc 56
#define Cc 192
#define NHc 6
#define Lc 3136
#define DHc 32
#define HIDc 768
#define NHEAD 96          // B*NH
#define Sc 32             // chunk length
#define NCHUNK 98         // chunks per head (98*32 = 3136)
#define NPAIR (NHEAD*NCHUNK)
#define ROWS (Bc*Lc)      // 50176
#define GR2 (ROWS/2)      // 25088 rows per MLP group (8 images)
#define ETAc (1.0f/32.0f)

typedef unsigned short u16;
typedef unsigned int u32;
typedef __attribute__((ext_vector_type(8))) short bf16x8;
typedef __attribute__((ext_vector_type(4))) float f32x4;
typedef __attribute__((ext_vector_type(16))) float f32x16;

__device__ __forceinline__ float b2f(u16 v){ u32 u = ((u32)v)<<16; float f; __builtin_memcpy(&f,&u,4); return f; }
__device__ __forceinline__ u16 f2b(float f){ u32 u; __builtin_memcpy(&u,&f,4); u32 r = u + 0x7FFFu + ((u>>16)&1u); return (u16)(r>>16); }
__device__ __forceinline__ f32x16 zero16(){ f32x16 z = {0,0,0,0,0,0,0,0,0,0,0,0,0,0,0,0}; return z; }

__device__ __forceinline__ void make_bfrags(const f32x16& t, int hi, bf16x8& b1, bf16x8& b2){
  u32 P[8], S[8];
  #pragma unroll
  for (int q=0;q<4;q++){
    #pragma unroll
    for (int j=0;j<2;j++){
      u32 r; float lo = t[4*q+2*j], hv = t[4*q+2*j+1];
      asm("v_cvt_pk_bf16_f32 %0, %1, %2" : "=v"(r) : "v"(lo), "v"(hv));
      P[2*q+j] = r;
    }
  }
  #pragma unroll
  for (int i=0;i<8;i++) S[i] = (u32)__shfl_xor((int)P[i], 32);
  union { u32 u[4]; bf16x8 v; } f1, f2;
  if (hi==0){ f1.u[0]=P[0]; f1.u[1]=P[1]; f1.u[2]=S[0]; f1.u[3]=S[1];
              f2.u[0]=P[4]; f2.u[1]=P[5]; f2.u[2]=S[4]; f2.u[3]=S[5]; }
  else      { f1.u[0]=S[2]; f1.u[1]=S[3]; f1.u[2]=P[2]; f1.u[3]=P[3];
              f2.u[0]=S[6]; f2.u[1]=S[7]; f2.u[2]=P[6]; f2.u[3]=P[7]; }
  b1 = f1.v; b2 = f2.v;
}

// ---------------- fused weight prep: 4 casts + 2 depthwise transposes ----------------
__global__ __launch_bounds__(256) void prep_kernel(
    const float* __restrict__ qkvw, const float* __restrict__ projw,
    const float* __restrict__ fc1w, const float* __restrict__ fc2w,
    const float* __restrict__ dwcw, const float* __restrict__ cpew,
    u16* __restrict__ wbqkv, u16* __restrict__ wbproj, u16* __restrict__ wbfc1,
    u16* __restrict__ wbfc2, float* __restrict__ dwt9, float* __restrict__ cwt9){
  int i = blockIdx.x*256 + threadIdx.x;
  if (i < 110592) wbqkv[i] = f2b(qkvw[i]);
  else if (i < 147456){ int j=i-110592; wbproj[j] = f2b(projw[j]); }
  else if (i < 294912){ int j=i-147456; wbfc1[j] = f2b(fc1w[j]); }
  else if (i < 442368){ int j=i-294912; wbfc2[j] = f2b(fc2w[j]); }
  else if (i < 449280){ int j=i-442368; int ch=j/9, t=j-ch*9; dwt9[t*HIDc+ch] = dwcw[j]; }
  else if (i < 451008){ int j=i-449280; int ch=j/9, t=j-ch*9; cwt9[t*Cc+ch] = cpew[j]; }
}

// ---------------- rope tables ----------------
__global__ __launch_bounds__(256) void rope_tab_kernel(float* __restrict__ ct, float* __restrict__ st){
  int i = blockIdx.x*256 + threadIdx.x;   // < Lc*96
  int l = i/96, p = i - l*96;
  int h = l/Wcc, w = l - h*Wcc;
  int kk = (p<48)? p : p-48;
  float th = powf(10000.f, -(float)kk/48.f);
  float ang = (float)((p<48)? h : w) * th;
  ct[i] = cosf(ang);
  st[i] = sinf(ang);
}

// ---------------- CPE depthwise conv + LN1 fused: block = 8 rows x 24 thr, 8 ch/thread ----------------
__global__ __launch_bounds__(192) void cpe_ln_kernel(const float* __restrict__ x, const float* __restrict__ cwt9,
                                                     const float* __restrict__ bs, const float* __restrict__ g,
                                                     const float* __restrict__ b,
                                                     u16* __restrict__ x1, u16* __restrict__ xn){
  __shared__ float ps[192], pq[192], smu[8], srs[8];
  int tid = threadIdx.x;
  int rl = tid/24, sub = tid - rl*24, ch0 = sub*8;
  int row = blockIdx.x*8 + rl;
  int l = row % Lc; int h = l/Wcc, w = l - h*Wcc;
  const float* xp = x + (size_t)row*Cc + ch0;
  float acc[8];
  { f32x4 b0 = *(const f32x4*)(bs+ch0), b1v = *(const f32x4*)(bs+ch0+4);
    acc[0]=b0[0];acc[1]=b0[1];acc[2]=b0[2];acc[3]=b0[3];
    acc[4]=b1v[0];acc[5]=b1v[1];acc[6]=b1v[2];acc[7]=b1v[3]; }
  #pragma unroll
  for (int kh=0;kh<3;kh++){
    int hh = h+kh-1; if (hh<0 || hh>=Hc) continue;
    #pragma unroll
    for (int kw=0;kw<3;kw++){
      int ww = w+kw-1; if (ww<0 || ww>=Wcc) continue;
      const float* ip = xp + ((kh-1)*Wcc + (kw-1))*Cc;
      f32x4 i0 = *(const f32x4*)ip, i1 = *(const f32x4*)(ip+4);
      const float* wp = cwt9 + (kh*3+kw)*Cc + ch0;
      f32x4 w0 = *(const f32x4*)wp, w1 = *(const f32x4*)(wp+4);
      acc[0] += i0[0]*w0[0]; acc[1] += i0[1]*w0[1]; acc[2] += i0[2]*w0[2]; acc[3] += i0[3]*w0[3];
      acc[4] += i1[0]*w1[0]; acc[5] += i1[1]*w1[1]; acc[6] += i1[2]*w1[2]; acc[7] += i1[3]*w1[3];
    }
  }
  float val[8];
  { f32x4 c0 = *(const f32x4*)xp, c1 = *(const f32x4*)(xp+4);
    val[0]=c0[0]+acc[0]; val[1]=c0[1]+acc[1]; val[2]=c0[2]+acc[2]; val[3]=c0[3]+acc[3];
    val[4]=c1[0]+acc[4]; val[5]=c1[1]+acc[5]; val[6]=c1[2]+acc[6]; val[7]=c1[3]+acc[7]; }
  float s8=0.f, q8=0.f;
  #pragma unroll
  for (int j=0;j<8;j++){ s8 += val[j]; q8 += val[j]*val[j]; }
  ps[tid]=s8; pq[tid]=q8;
  __syncthreads();
  if (tid < 8){
    float s=0.f, q=0.f;
    #pragma unroll
    for (int k=0;k<24;k++){ s += ps[tid*24+k]; q += pq[tid*24+k]; }
    float mu = s*(1.f/Cc);
    float var = q*(1.f/Cc) - mu*mu;
    smu[tid] = mu; srs[tid] = rsqrtf(var + 1e-5f);
  }
  __syncthreads();
  float mu = smu[rl], rstd = srs[rl];
  union { bf16x8 v; u16 s[8]; } o1, o2;
  f32x4 g0 = *(const f32x4*)(g+ch0), g1 = *(const f32x4*)(g+ch0+4);
  f32x4 bb0 = *(const f32x4*)(b+ch0), bb1 = *(const f32x4*)(b+ch0+4);
  float gg[8] = {g0[0],g0[1],g0[2],g0[3],g1[0],g1[1],g1[2],g1[3]};
  float bbv[8] = {bb0[0],bb0[1],bb0[2],bb0[3],bb1[0],bb1[1],bb1[2],bb1[3]};
  #pragma unroll
  for (int j=0;j<8;j++){
    o1.s[j] = f2b(val[j]);
    o2.s[j] = f2b((val[j]-mu)*rstd*gg[j] + bbv[j]);
  }
  *(bf16x8*)(x1 + (size_t)row*Cc + ch0) = o1.v;
  *(bf16x8*)(xn + (size_t)row*Cc + ch0) = o2.v;
}

// ---------------- LayerNorm -> bf16 (bf16 input) ----------------
__global__ __launch_bounds__(256) void ln_kernel(const u16* __restrict__ xb, const float* __restrict__ g,
                                                 const float* __restrict__ b, u16* __restrict__ out){
  int row = blockIdx.x*4 + (threadIdx.x>>6);
  int lane = threadIdx.x & 63;
  const u16* xr = xb + (size_t)row*Cc;
  float v0 = b2f(xr[lane]), v1 = b2f(xr[lane+64]), v2 = b2f(xr[lane+128]);
  float s = v0+v1+v2;
  float q = v0*v0 + v1*v1 + v2*v2;
  #pragma unroll
  for (int off=32; off; off>>=1){ s += __shfl_xor(s, off); q += __shfl_xor(q, off); }
  float mu = s*(1.f/Cc);
  float var = q*(1.f/Cc) - mu*mu;
  float rstd = rsqrtf(var + 1e-5f);
  u16* orow = out + (size_t)row*Cc;
  orow[lane]     = f2b((v0-mu)*rstd*g[lane]     + b[lane]);
  orow[lane+64]  = f2b((v1-mu)*rstd*g[lane+64]  + b[lane+64]);
  orow[lane+128] = f2b((v2-mu)*rstd*g[lane+128] + b[lane+128]);
}

// ---------------- LDS-staged GEMM, BLKM=64, coalesced LDS epilogue ----------------
// MODE 0: qkv + fused rope  (y=0: q->rope*scale->q_s; y=1: k->rope->k_s; y=2: v->vdst)
// MODE 1: proj: bf16 out = v + b2f(residb)   [x2b, elementwise-aliased with residb]
// MODE 2: fc1:  bf16 out = gelu(v), width HIDc
// MODE 3: fc2:  fp32 out = v + b2f(residb)
template<int MODE, int KT>
__global__ __launch_bounds__(256) void gemm_kernel(
    const u16* __restrict__ A, const u16* __restrict__ Wt,
    const float* __restrict__ bias,
    float* __restrict__ outf, u16* __restrict__ outb, u16* __restrict__ vdst,
    const u16* __restrict__ residb,
    const float* __restrict__ ct, const float* __restrict__ st,
    u16* __restrict__ q_s, u16* __restrict__ k_s)
{
  constexpr int NCH = KT/192;
  __shared__ __align__(16) char smem[64*200*2];   // As[64][200] u16 | Os32[64][100] f32 | Osu[64][200] u16
  u16* As = (u16*)smem;
  float* Os32 = (float*)smem;
  u16* Osu = (u16*)smem;
  int tid = threadIdx.x;
  int wid = tid>>6, lane = tid&63;
  int wr = wid>>1, wc = wid&1;
  int m0 = blockIdx.x*64;
  int nblk = blockIdx.y*192;
  int n0 = nblk + wc*96;
  int ar = lane&15, kg = lane>>4;
  f32x4 acc[2][6];
  #pragma unroll
  for (int f=0;f<2;f++)
    #pragma unroll
    for (int c=0;c<6;c++){ f32x4 z = {0.f,0.f,0.f,0.f}; acc[f][c] = z; }
  bf16x8 bcur[6], bnxt[6];
  #pragma unroll
  for (int c=0;c<6;c++) bcur[c] = *(const bf16x8*)(Wt + (size_t)(n0 + c*16 + ar)*KT + kg*8);
  #pragma unroll
  for (int ch=0; ch<NCH; ch++){
    if (ch>0) __syncthreads();
    #pragma unroll
    for (int j=0;j<6;j++){
      int g = j*256 + tid;
      int grow = g/24, gcol = (g - grow*24)*8;
      bf16x8 v = *(const bf16x8*)(A + (size_t)(m0+grow)*KT + ch*192 + gcol);
      *(bf16x8*)(As + grow*200 + gcol) = v;
    }
    __syncthreads();
    #pragma unroll
    for (int kc=0;kc<6;kc++){
      int s = ch*6 + kc;
      if (s+1 < NCH*6){
        int koff = ((s+1)/6)*192 + ((s+1)%6)*32 + kg*8;
        #pragma unroll
        for (int c=0;c<6;c++) bnxt[c] = *(const bf16x8*)(Wt + (size_t)(n0 + c*16 + ar)*KT + koff);
      }
      bf16x8 af[2];
      #pragma unroll
      for (int f=0;f<2;f++)
        af[f] = *(const bf16x8*)(As + (wr*32 + f*16 + ar)*200 + kc*32 + kg*8);
      #pragma unroll
      for (int f=0;f<2;f++)
        #pragma unroll
        for (int c=0;c<6;c++)
          acc[f][c] = __builtin_amdgcn_mfma_f32_16x16x32_bf16(af[f], bcur[c], acc[f][c], 0,0,0);
      #pragma unroll
      for (int c=0;c<6;c++) bcur[c] = bnxt[c];
    }
  }
  __syncthreads();
  if (MODE != 3){
    #pragma unroll
    for (int f=0;f<2;f++){
      #pragma unroll
      for (int c=0;c<6;c++){
        float bv = bias[n0 + c*16 + ar];
        #pragma unroll
        for (int j=0;j<4;j++){
          float v = acc[f][c][j] + bv;
          if (MODE==2) v = 0.5f*v*(1.f + erff(v*0.70710678118654752f));
          Osu[(wr*32 + f*16 + kg*4 + j)*200 + wc*96 + c*16 + ar] = f2b(v);
        }
      }
    }
    __syncthreads();
    #pragma unroll
    for (int j=0;j<6;j++){
      int g = j*256 + tid;
      int grow = g/24, gcol = (g - grow*24)*8;
      bf16x8 v = *(const bf16x8*)(Osu + grow*200 + gcol);
      int row = m0 + grow;
      if (MODE==2){
        *(bf16x8*)(outb + (size_t)row*HIDc + nblk + gcol) = v;
      } else if (MODE==1){
        const u16* rp = residb + (size_t)row*Cc + gcol;
        bf16x8 rv = *(const bf16x8*)rp;
        union { bf16x8 v; u16 s[8]; } o;
        #pragma unroll
        for (int t=0;t<8;t++) o.s[t] = f2b(b2f((u16)v[t]) + b2f((u16)rv[t]));
        *(bf16x8*)(outb + (size_t)row*Cc + gcol) = o.v;
      } else {   // MODE 0: qkv with fused rope
        int bb = row/Lc; int l = row - bb*Lc;
        int nh = gcol>>5, d = gcol&31;
        if (nblk < 384){
          bool isq = (nblk == 0);
          int p0 = gcol>>1;
          f32x4 cv = *(const f32x4*)(ct + l*96 + p0);
          f32x4 sv = *(const f32x4*)(st + l*96 + p0);
          float sc = isq ? 0.1767766952966369f : 1.0f;
          union { bf16x8 v; u16 s[8]; } o;
          #pragma unroll
          for (int t=0;t<4;t++){
            float re = b2f((u16)v[2*t]), im = b2f((u16)v[2*t+1]);
            o.s[2*t]   = f2b((cv[t]*re - sv[t]*im)*sc);
            o.s[2*t+1] = f2b((sv[t]*re + cv[t]*im)*sc);
          }
          u16* dst = (isq ? q_s : k_s) + (((size_t)(bb*NHc+nh))*Lc + l)*DHc + d;
          *(bf16x8*)dst = o.v;
        } else {
          *(bf16x8*)(vdst + (((size_t)(bb*NHc+nh))*Lc + l)*DHc + d) = v;
        }
      }
    }
  } else {
    #pragma unroll
    for (int half=0; half<2; half++){
      if (wc==half){
        #pragma unroll
        for (int f=0;f<2;f++){
          #pragma unroll
          for (int c=0;c<6;c++){
            float bv = bias[n0 + c*16 + ar];
            #pragma unroll
            for (int j=0;j<4;j++)
              Os32[(wr*32 + f*16 + kg*4 + j)*100 + c*16 + ar] = acc[f][c][j] + bv;
          }
        }
      }
      __syncthreads();
      #pragma unroll
      for (int j=0;j<6;j++){
        int g = j*256 + tid;
        int grow = g/24, qcol = (g - grow*24)*4;
        f32x4 v = *(const f32x4*)(Os32 + grow*100 + qcol);
        int row = m0 + grow, colg = half*96 + qcol;
        const u16* rp = residb + (size_t)row*Cc + colg;
        v[0] += b2f(rp[0]); v[1] += b2f(rp[1]); v[2] += b2f(rp[2]); v[3] += b2f(rp[3]);
        *(f32x4*)(outf + (size_t)row*Cc + colg) = v;
      }
      if (half==0) __syncthreads();
    }
  }
}

// ---------------- phase A: per (head,chunk) solve -> U, -R, A'=-K^T R (frags), B=K^T U ----------------
__global__ __launch_bounds__(64) void ttta_kernel(const u16* __restrict__ k_s, const u16* __restrict__ v_s,
                                                  u16* __restrict__ u_s, u16* __restrict__ rn_s,
                                                  u16* __restrict__ af_s, u16* __restrict__ bc_s){
  __shared__ float Gl[1024];
  __shared__ u16 LK[32*40];
  __shared__ float LU[32*33];
  __shared__ float LR[32*33];
  int pair = blockIdx.x;
  int head = pair / NCHUNK;
  int l0 = (pair - head*NCHUNK) * Sc;
  int lane = threadIdx.x; int rr = lane&31; int hi = lane>>5; int ks = hi*8;
  const u16* kb = k_s + ((size_t)head*Lc + l0)*DHc;
  bf16x8 a0 = *(const bf16x8*)(kb + rr*32 + ks);
  bf16x8 a1 = *(const bf16x8*)(kb + rr*32 + 16 + ks);
  *(bf16x8*)(LK + rr*40 + ks) = a0;
  *(bf16x8*)(LK + rr*40 + 16 + ks) = a1;
  f32x16 g = zero16();
  g = __builtin_amdgcn_mfma_f32_32x32x16_bf16(a0, a0, g, 0,0,0);
  g = __builtin_amdgcn_mfma_f32_32x32x16_bf16(a1, a1, g, 0,0,0);
  #pragma unroll
  for (int reg=0;reg<16;reg++){
    int i = (reg&3) + 8*(reg>>2) + 4*hi;
    Gl[i*32 + rr] = ETAc * g[reg];
  }
  __syncthreads();
  float X[32];
  if (lane < 32){
    #pragma unroll
    for (int i=0;i<32;i++) X[i] = ETAc * b2f(v_s[((size_t)head*Lc + l0 + i)*DHc + lane]);
  } else {
    int m = lane-32;
    #pragma unroll
    for (int i=0;i<32;i++) X[i] = ETAc * b2f(kb[i*32 + m]);
  }
  #pragma unroll
  for (int i=1;i<32;i++){
    float a = X[i];
    #pragma unroll
    for (int j=0;j<i;j++) a -= Gl[i*32+j]*X[j];
    X[i] = a;
  }
  if (lane < 32){
    u16* dst = u_s + (size_t)pair*1024 + lane;
    #pragma unroll
    for (int i=0;i<32;i++) dst[i*32] = f2b(X[i]);
    #pragma unroll
    for (int i=0;i<32;i++) LU[lane*33 + i] = X[i];
  } else {
    u16* dst = rn_s + (size_t)pair*1024 + (lane&31);
    #pragma unroll
    for (int i=0;i<32;i++) dst[i*32] = f2b(-X[i]);
    #pragma unroll
    for (int i=0;i<32;i++) LR[(lane&31)*33 + i] = X[i];
  }
  __syncthreads();
  union { bf16x8 v; u16 s[8]; } kc1, kc2, uc1, uc2, rc1, rc2;
  #pragma unroll
  for (int s=0;s<8;s++){
    kc1.s[s] = LK[(ks+s)*40 + rr];
    kc2.s[s] = LK[(16+ks+s)*40 + rr];
    uc1.s[s] = f2b(LU[rr*33 + ks+s]);
    uc2.s[s] = f2b(LU[rr*33 + 16+ks+s]);
    rc1.s[s] = f2b(LR[rr*33 + ks+s]);
    rc2.s[s] = f2b(LR[rr*33 + 16+ks+s]);
  }
  f32x16 bacc = zero16();
  bacc = __builtin_amdgcn_mfma_f32_32x32x16_bf16(kc1.v, uc1.v, bacc, 0,0,0);
  bacc = __builtin_amdgcn_mfma_f32_32x32x16_bf16(kc2.v, uc2.v, bacc, 0,0,0);
  union { bf16x8 v; u16 s[8]; } bo1, bo2;
  #pragma unroll
  for (int r=0;r<8;r++){ bo1.s[r] = f2b(bacc[r]); bo2.s[r] = f2b(bacc[8+r]); }
  *(bf16x8*)(bc_s + (size_t)pair*1024 + lane*16) = bo1.v;
  *(bf16x8*)(bc_s + (size_t)pair*1024 + lane*16 + 8) = bo2.v;
  f32x16 aacc = zero16();
  aacc = __builtin_amdgcn_mfma_f32_32x32x16_bf16(rc1.v, kc1.v, aacc, 0,0,0);
  aacc = __builtin_amdgcn_mfma_f32_32x32x16_bf16(rc2.v, kc2.v, aacc, 0,0,0);
  f32x16 an;
  #pragma unroll
  for (int r=0;r<16;r++) an[r] = -aacc[r];
  bf16x8 f1, f2;
  make_bfrags(an, hi, f1, f2);
  *(bf16x8*)(af_s + (size_t)pair*1024 + lane*16) = f1;
  *(bf16x8*)(af_s + (size_t)pair*1024 + lane*16 + 8) = f2;
}

// ---------------- phase B: MFMA affine scan  T_{c+1} = T_c + A'_c T_c + B_c ----------------
__global__ __launch_bounds__(64) void tttb_kernel(const u16* __restrict__ af_s, const u16* __restrict__ bc_s,
                                                  const float* __restrict__ W0, u16* __restrict__ w_snap){
  int head = blockIdx.x; int nh = head % NHc;
  int lane = threadIdx.x; int rr = lane&31; int hi = lane>>5;
  f32x16 T;
  const float* w0r = W0 + nh*1024 + rr*32 + 4*hi;
  #pragma unroll
  for (int q=0;q<4;q++){
    f32x4 v = *(const f32x4*)(w0r + 8*q);
    T[4*q+0]=v[0]; T[4*q+1]=v[1]; T[4*q+2]=v[2]; T[4*q+3]=v[3];
  }
  size_t hb = (size_t)head*NCHUNK;
  const bf16x8* afp = (const bf16x8*)(af_s + hb*1024);
  const bf16x8* bcp = (const bf16x8*)(bc_s + hb*1024);
  bf16x8 A1 = afp[lane*2], A2 = afp[lane*2+1];
  bf16x8 Bv1 = bcp[lane*2], Bv2 = bcp[lane*2+1];
  bf16x8 b1, b2;
  make_bfrags(T, hi, b1, b2);
  for (int c=0;c<NCHUNK;c++){
    bf16x8 nA1=A1, nA2=A2, nB1=Bv1, nB2=Bv2;
    if (c+1 < NCHUNK){
      int base = (c+1)*128 + lane*2;
      nA1 = afp[base]; nA2 = afp[base+1];
      nB1 = bcp[base]; nB2 = bcp[base+1];
    }
    u16* wrow = w_snap + (hb + c)*1024 + rr*32;
    *(bf16x8*)(wrow + hi*8) = b1;
    *(bf16x8*)(wrow + 16 + hi*8) = b2;
    f32x16 acc;
    #pragma unroll
    for (int r=0;r<8;r++){ acc[r] = T[r] + b2f((u16)Bv1[r]); acc[8+r] = T[8+r] + b2f((u16)Bv2[r]); }
    acc = __builtin_amdgcn_mfma_f32_32x32x16_bf16(A1, b1, acc, 0,0,0);
    acc = __builtin_amdgcn_mfma_f32_32x32x16_bf16(A2, b2, acc, 0,0,0);
    T = acc;
    make_bfrags(T, hi, b1, b2);
    A1=nA1; A2=nA2; Bv1=nB1; Bv2=nB2;
  }
}

// ---------------- phase C: O = Q*T0 + tril(Q K^T)*(U - R*T0) ----------------
__global__ __launch_bounds__(64) void tttc_kernel(const u16* __restrict__ q_s, const u16* __restrict__ k_s,
                                                  const u16* __restrict__ w_snap, const u16* __restrict__ u_s,
                                                  const u16* __restrict__ rn_s, u16* __restrict__ o_bf){
  __shared__ __align__(16) u16 Pl[32*40];
  int pair = blockIdx.x;
  int head = pair / NCHUNK;
  int ch = pair - head*NCHUNK;
  int l0 = ch*Sc;
  int lane = threadIdx.x; int rr = lane&31; int hi = lane>>5; int ks = hi*8;
  const u16* qb = q_s + ((size_t)head*Lc + l0)*DHc;
  const u16* kb = k_s + ((size_t)head*Lc + l0)*DHc;
  bf16x8 q0 = *(const bf16x8*)(qb + rr*32 + ks);
  bf16x8 q1 = *(const bf16x8*)(qb + rr*32 + 16 + ks);
  bf16x8 k0 = *(const bf16x8*)(kb + rr*32 + ks);
  bf16x8 k1 = *(const bf16x8*)(kb + rr*32 + 16 + ks);
  f32x16 p = zero16();
  p = __builtin_amdgcn_mfma_f32_32x32x16_bf16(q0, k0, p, 0,0,0);
  p = __builtin_amdgcn_mfma_f32_32x32x16_bf16(q1, k1, p, 0,0,0);
  #pragma unroll
  for (int reg=0;reg<16;reg++){
    int i = (reg&3)+8*(reg>>2)+4*hi;
    Pl[i*40+rr] = (rr<=i) ? f2b(p[reg]) : (u16)0;
  }
  const u16* wsb = w_snap + (size_t)pair*1024;
  bf16x8 tb0 = *(const bf16x8*)(wsb + rr*32 + ks);
  bf16x8 tb1 = *(const bf16x8*)(wsb + rr*32 + 16 + ks);
  const u16* ub = u_s + (size_t)pair*1024;
  f32x16 wr;
  #pragma unroll
  for (int r=0;r<16;r++){
    int i = (r&3)+8*(r>>2)+4*hi;
    wr[r] = b2f(ub[i*32 + rr]);
  }
  const u16* rb = rn_s + (size_t)pair*1024;
  bf16x8 rn0 = *(const bf16x8*)(rb + rr*32 + ks);
  bf16x8 rn1 = *(const bf16x8*)(rb + rr*32 + 16 + ks);
  wr = __builtin_amdgcn_mfma_f32_32x32x16_bf16(rn0, tb0, wr, 0,0,0);
  wr = __builtin_amdgcn_mfma_f32_32x32x16_bf16(rn1, tb1, wr, 0,0,0);
  bf16x8 wb0, wb1;
  make_bfrags(wr, hi, wb0, wb1);
  __syncthreads();
  f32x16 o = zero16();
  o = __builtin_amdgcn_mfma_f32_32x32x16_bf16(q0, tb0, o, 0,0,0);
  o = __builtin_amdgcn_mfma_f32_32x32x16_bf16(q1, tb1, o, 0,0,0);
  bf16x8 pa0 = *(const bf16x8*)(Pl + rr*40 + ks);
  bf16x8 pa1 = *(const bf16x8*)(Pl + rr*40 + 16 + ks);
  o = __builtin_amdgcn_mfma_f32_32x32x16_bf16(pa0, wb0, o, 0,0,0);
  o = __builtin_amdgcn_mfma_f32_32x32x16_bf16(pa1, wb1, o, 0,0,0);
  int bb = head/NHc, nh = head - bb*NHc;
  #pragma unroll
  for (int reg=0;reg<16;reg++){
    int i = (reg&3)+8*(reg>>2)+4*hi;
    o_bf[((size_t)(bb*Lc + l0 + i))*Cc + nh*32 + rr] = f2b(o[reg]);
  }
}

// ---------------- MLP depthwise conv (HID=768) + gelu, 8 channels/thread ----------------
__global__ __launch_bounds__(256) void dwc_kernel(const u16* __restrict__ h1, const float* __restrict__ wt9,
                                                  const float* __restrict__ bs, u16* __restrict__ h2, int row0){
  int gid = blockIdx.x*256 + threadIdx.x;   // < GR2*96
  int cg = gid % 96; int lrow = gid / 96; int ch0 = cg*8;
  int row = row0 + lrow;
  int l = row % Lc; int h = l/Wcc, w = l - h*Wcc;
  const u16* hp = h1 + (size_t)lrow*HIDc + ch0;
  float acc[8];
  { f32x4 b0 = *(const f32x4*)(bs+ch0), b1v = *(const f32x4*)(bs+ch0+4);
    acc[0]=b0[0];acc[1]=b0[1];acc[2]=b0[2];acc[3]=b0[3];
    acc[4]=b1v[0];acc[5]=b1v[1];acc[6]=b1v[2];acc[7]=b1v[3]; }
  #pragma unroll
  for (int kh=0;kh<3;kh++){
    int hh = h+kh-1; if (hh<0 || hh>=Hc) continue;
    #pragma unroll
    for (int kw=0;kw<3;kw++){
      int ww = w+kw-1; if (ww<0 || ww>=Wcc) continue;
      bf16x8 iv = *(const bf16x8*)(hp + ((kh-1)*Wcc + (kw-1))*HIDc);
      const float* wp = wt9 + (kh*3+kw)*HIDc + ch0;
      f32x4 w0 = *(const f32x4*)wp, w1 = *(const f32x4*)(wp+4);
      acc[0] += b2f((u16)iv[0])*w0[0]; acc[1] += b2f((u16)iv[1])*w0[1];
      acc[2] += b2f((u16)iv[2])*w0[2]; acc[3] += b2f((u16)iv[3])*w0[3];
      acc[4] += b2f((u16)iv[4])*w1[0]; acc[5] += b2f((u16)iv[5])*w1[1];
      acc[6] += b2f((u16)iv[6])*w1[2]; acc[7] += b2f((u16)iv[7])*w1[3];
    }
  }
  bf16x8 cv = *(const bf16x8*)hp;
  union { bf16x8 v; u16 s[8]; } ov;
  #pragma unroll
  for (int j=0;j<8;j++){
    float v = b2f((u16)cv[j]) + acc[j];
    ov.s[j] = f2b(0.5f*v*(1.f + erff(v*0.70710678118654752f)));
  }
  *(bf16x8*)(h2 + (size_t)lrow*HIDc + ch0) = ov.v;
}

// ---------------- launch ----------------
extern "C" void kernel_launch(void* const* d_in, const int* in_sizes, int n_in,
                              void* d_out, int out_size, void* d_ws, size_t ws_size,
                              hipStream_t stream){
  const float* x     = (const float*)d_in[0];
  const float* cpe_w = (const float*)d_in[1];
  const float* cpe_b = (const float*)d_in[2];
  const float* n1_g  = (const float*)d_in[3];
  const float* n1_b  = (const float*)d_in[4];
  const float* qkv_w = (const float*)d_in[5];
  const float* qkv_b = (const float*)d_in[6];
  const float* W0    = (const float*)d_in[7];
  const float* proj_w= (const float*)d_in[8];
  const float* proj_b= (const float*)d_in[9];
  const float* n2_g  = (const float*)d_in[10];
  const float* n2_b  = (const float*)d_in[11];
  const float* fc1_w = (const float*)d_in[12];
  const float* fc1_b = (const float*)d_in[13];
  const float* dwc_w = (const float*)d_in[14];
  const float* dwc_b = (const float*)d_in[15];
  const float* fc2_w = (const float*)d_in[16];
  const float* fc2_b = (const float*)d_in[17];

  char* ws = (char*)d_ws;
  size_t off = 0;
  auto alloc = [&](size_t bytes)->char*{
    char* p = ws + off;
    off += (bytes + 255) & ~(size_t)255;
    return p;
  };
  u16* wbqkv = (u16*)alloc((size_t)576*192*2);
  u16* wbproj= (u16*)alloc((size_t)192*192*2);
  u16* wbfc1 = (u16*)alloc((size_t)768*192*2);
  u16* wbfc2 = (u16*)alloc((size_t)192*768*2);
  float* dwt9 = (float*)alloc((size_t)9*HIDc*4);
  float* cwt9 = (float*)alloc((size_t)9*Cc*4);
  float* ctab = (float*)alloc((size_t)Lc*96*4);
  float* stab = (float*)alloc((size_t)Lc*96*4);
  u16* regA = (u16*)alloc((size_t)ROWS*Cc*2);       // x1 -> x2b (elementwise in-place at proj)
  u16* regB = (u16*)alloc((size_t)ROWS*Cc*2);       // xn -> obf -> xn2
  u16* regC = (u16*)alloc((size_t)NHEAD*Lc*DHc*2);  // qs
  u16* regD = (u16*)alloc((size_t)NHEAD*Lc*DHc*2);  // vs -> wsn -> h1[0:half]
  u16* regE = (u16*)alloc((size_t)NHEAD*Lc*DHc*2);  // ksb -> h1[half:]
  u16* rn_s = (u16*)alloc((size_t)NPAIR*1024*2);    // -R -> h2[0:half]
  u16* af_s = (u16*)alloc((size_t)NPAIR*1024*2);    // A' frags -> h2[half:]
  // d_out (38.5 MB): [us | bc] during TTT -> final fp32 output
  u16* us = (u16*)d_out;
  u16* bc = us + (size_t)NPAIR*1024;

  u16* x1 = regA;
  u16* x2b = regA;  // proj epilogue: elementwise read-resid-then-write, same address, same thread
  u16* xn = regB;
  u16* obf = regB;
  u16* xn2 = regB;
  u16* qs = regC;
  u16* vs = regD;
  u16* wsn = regD;  // written by tttb after ttta fully consumed vs
  u16* ksb = regE;
  u16* h1 = regD;   // regD+regE contiguous = GR2*768*2 bytes
  u16* h2 = rn_s;   // rn_s+af_s contiguous = GR2*768*2 bytes

  prep_kernel<<<(451008+255)/256,256,0,stream>>>(qkv_w, proj_w, fc1_w, fc2_w, dwc_w, cpe_w,
                                                 wbqkv, wbproj, wbfc1, wbfc2, dwt9, cwt9);
  rope_tab_kernel<<<(Lc*96)/256,256,0,stream>>>(ctab, stab);

  cpe_ln_kernel<<<ROWS/8,192,0,stream>>>(x, cwt9, cpe_b, n1_g, n1_b, x1, xn);
  { dim3 g(ROWS/64, 3); gemm_kernel<0,192><<<g,256,0,stream>>>(xn, wbqkv, qkv_b,
      nullptr, nullptr, vs, nullptr, ctab, stab, qs, ksb); }
  ttta_kernel<<<NPAIR,64,0,stream>>>(ksb, vs, us, rn_s, af_s, bc);
  tttb_kernel<<<NHEAD,64,0,stream>>>(af_s, bc, W0, wsn);
  tttc_kernel<<<NPAIR,64,0,stream>>>(qs, ksb, wsn, us, rn_s, obf);
  { dim3 g(ROWS/64, 1); gemm_kernel<1,192><<<g,256,0,stream>>>(obf, wbproj, proj_b,
      nullptr, x2b, nullptr, x1, nullptr, nullptr, nullptr, nullptr); }
  ln_kernel<<<ROWS/4,256,0,stream>>>(x2b, n2_g, n2_b, xn2);
  for (int g4=0; g4<2; g4++){
    const u16* a_in = xn2 + (size_t)g4*GR2*Cc;
    float* xo = (float*)d_out + (size_t)g4*GR2*Cc;
    const u16* res = x2b + (size_t)g4*GR2*Cc;
    { dim3 g(GR2/64, 4); gemm_kernel<2,192><<<g,256,0,stream>>>(a_in, wbfc1, fc1_b,
        nullptr, h1, nullptr, nullptr, nullptr, nullptr, nullptr, nullptr); }
    dwc_kernel<<<(GR2*96)/256,256,0,stream>>>(h1, dwt9, dwc_b, h2, g4*GR2);
    { dim3 g(GR2/64, 1); gemm_kernel<3,768><<<g,256,0,stream>>>(h2, wbfc2, fc2_b,
        xo, nullptr, nullptr, res, nullptr, nullptr, nullptr, nullptr); }
  }
}